// Round 4
// baseline (1041.532 us; speedup 1.0000x reference)
//
#include <hip/hip_runtime.h>
#include <math.h>

#define INDIM 256
#define HID 128
#define HEADS 4
#define NGAT 3
#define LN_EPS 1e-5f
#define SLOPE 0.2f
#define MPAD 40064  // 313 * 128
#define LOG2E 1.4426950408889634f

typedef __attribute__((ext_vector_type(8))) short short8;
typedef __attribute__((ext_vector_type(4))) float f32x4;

__device__ inline float wsum(float v) {
#pragma unroll
  for (int m = 1; m < 64; m <<= 1) v += __shfl_xor(v, m, 64);
  return v;
}
__device__ inline float wmax(float v) {
#pragma unroll
  for (int m = 1; m < 64; m <<= 1) v = fmaxf(v, __shfl_xor(v, m, 64));
  return v;
}
// leaky_relu then scale to exp2 domain
__device__ inline float lk2(float v) { return fmaxf(v, SLOPE * v) * LOG2E; }

__device__ inline unsigned short f2b(float f) {
  unsigned u = __float_as_uint(f);
  unsigned r = (u + 0x7FFFu + ((u >> 16) & 1u)) >> 16;
  return (unsigned short)r;
}
__device__ inline void unp8(const uint4 v, float f[8]) {
  f[0] = __uint_as_float(v.x << 16);
  f[1] = __uint_as_float(v.x & 0xFFFF0000u);
  f[2] = __uint_as_float(v.y << 16);
  f[3] = __uint_as_float(v.y & 0xFFFF0000u);
  f[4] = __uint_as_float(v.z << 16);
  f[5] = __uint_as_float(v.z & 0xFFFF0000u);
  f[6] = __uint_as_float(v.w << 16);
  f[7] = __uint_as_float(v.w & 0xFFFF0000u);
}

// ---------------- CSR construction ----------------
__global__ void k_deg(const int* __restrict__ ei, int E, int N, int* __restrict__ deg) {
  int e = blockIdx.x * blockDim.x + threadIdx.x;
  if (e >= E + N) return;
  int dst = (e < E) ? ei[E + e] : (e - E);
  atomicAdd(&deg[dst], 1);
}

__global__ void k_scan1(const int* __restrict__ deg, int N, int* __restrict__ bsums) {
  __shared__ int s[256];
  int gid = blockIdx.x * 256 + threadIdx.x;
  s[threadIdx.x] = (gid < N) ? deg[gid] : 0;
  __syncthreads();
  for (int off = 128; off > 0; off >>= 1) {
    if (threadIdx.x < off) s[threadIdx.x] += s[threadIdx.x + off];
    __syncthreads();
  }
  if (threadIdx.x == 0) bsums[blockIdx.x] = s[0];
}

__global__ void k_scan2(int* __restrict__ bsums, int nblk, int* __restrict__ rowptr, int N) {
  if (threadIdx.x == 0 && blockIdx.x == 0) {
    int run = 0;
    for (int i = 0; i < nblk; ++i) { int t = bsums[i]; bsums[i] = run; run += t; }
    rowptr[N] = run;
  }
}

__global__ void k_scan3(const int* __restrict__ deg, int N, const int* __restrict__ bsums,
                        int* __restrict__ rowptr, int* __restrict__ cursor,
                        float* __restrict__ dinv) {
  __shared__ int s[256];
  int gid = blockIdx.x * 256 + threadIdx.x;
  int v = (gid < N) ? deg[gid] : 0;
  s[threadIdx.x] = v;
  __syncthreads();
  for (int off = 1; off < 256; off <<= 1) {
    int t = (threadIdx.x >= off) ? s[threadIdx.x - off] : 0;
    __syncthreads();
    s[threadIdx.x] += t;
    __syncthreads();
  }
  if (gid < N) {
    int ex = bsums[blockIdx.x] + s[threadIdx.x] - v;
    rowptr[gid] = ex;
    cursor[gid] = ex;
    dinv[gid] = rsqrtf((float)v);
  }
}

__global__ void k_fill(const int* __restrict__ ei, int E, int N,
                       int* __restrict__ cursor, int* __restrict__ csr) {
  int e = blockIdx.x * blockDim.x + threadIdx.x;
  if (e >= E + N) return;
  int src, dst;
  if (e < E) { src = ei[e]; dst = ei[E + e]; } else { src = dst = e - E; }
  int pos = atomicAdd(&cursor[dst], 1);
  csr[pos] = src;
}

// ---------------- weight prep ----------------
// proj_W [INDIM][HID] -> WtP [HID][INDIM] bf16
__global__ void k_wt(const float* __restrict__ W, unsigned short* __restrict__ Wt,
                     int K, int Nc) {
  int idx = blockIdx.x * 256 + threadIdx.x;
  if (idx >= K * Nc) return;
  int k = idx / Nc, n = idx % Nc;
  Wt[n * K + k] = f2b(W[idx]);
}

// gat_W [NGAT][128 k][512 (h*128+c)] -> Wt2 [NGAT][128 c][512 (h*128+k)] * 0.25
// (stacked per-head weights, transposed for the post-agg GEMM, head-mean folded)
__global__ void k_wt2(const float* __restrict__ W, unsigned short* __restrict__ Wt) {
  int idx = blockIdx.x * 256 + threadIdx.x;
  if (idx >= NGAT * HID * HEADS * HID) return;
  int l = idx / (HID * HEADS * HID);
  int rem = idx - l * HID * HEADS * HID;
  int k = rem / (HEADS * HID);
  int col = rem % (HEADS * HID);
  int hh = col >> 7, c = col & 127;
  Wt[(size_t)l * (HID * HEADS * HID) + (size_t)c * (HEADS * HID) + hh * HID + k] =
      f2b(W[idx] * 0.25f);
}

// w_s[l][h][k] = sum_c gat_W[l][k][h*128+c] * att_src[l][h][c]  (and w_d)
__global__ void k_wvec(const float* __restrict__ W, const float* __restrict__ atts,
                       const float* __restrict__ attd, float* __restrict__ w_s,
                       float* __restrict__ w_d) {
  int lane = threadIdx.x & 63;
  int idx = blockIdx.x * 4 + (threadIdx.x >> 6);
  if (idx >= NGAT * HEADS * HID) return;
  int l = idx / (HEADS * HID);
  int rem = idx - l * (HEADS * HID);
  int hh = rem >> 7, k = rem & 127;
  const float2 w2 = *(const float2*)(W + ((size_t)(l * HID + k)) * (HEADS * HID) +
                                     hh * HID + lane * 2);
  const float2 s2 = *(const float2*)(atts + (size_t)(l * HEADS + hh) * HID + lane * 2);
  const float2 d2 = *(const float2*)(attd + (size_t)(l * HEADS + hh) * HID + lane * 2);
  float ps = w2.x * s2.x + w2.y * s2.y;
  float pd = w2.x * d2.x + w2.y * d2.y;
  ps = wsum(ps);
  pd = wsum(pd);
  if (lane == 0) { w_s[idx] = ps; w_d[idx] = pd; }
}

// ---------------- projection GEMM: h = x(fp32) @ WtP^T + b ----------------
template <int K>
__global__ __launch_bounds__(256) void k_mm(const float* __restrict__ Af,
                                            const unsigned short* __restrict__ Bt,
                                            const float* __restrict__ bias,
                                            float* __restrict__ Cf,
                                            unsigned short* __restrict__ Cb,
                                            int Nc, int Mreal) {
  const int wid = threadIdx.x >> 6;
  const int lane = threadIdx.x & 63;
  const int bm = blockIdx.x * 128;
  const int wr = (wid >> 1) * 64;
  const int wc = (wid & 1) * 64;
  const int l15 = lane & 15;
  const int lk = (lane >> 4) * 8;
  f32x4 acc[4][4] = {};
  const unsigned short* Bp = Bt + (size_t)(wc + l15) * K + lk;
  for (int k0 = 0; k0 < K; k0 += 32) {
    short8 af[4], bfr[4];
#pragma unroll
    for (int i = 0; i < 4; ++i) {
      const int row = bm + wr + l15 + i * 16;
      if (row < Mreal) {
        const float* ap = Af + (size_t)row * K + lk + k0;
        float4 u = *(const float4*)ap;
        float4 v = *(const float4*)(ap + 4);
        af[i][0] = (short)f2b(u.x); af[i][1] = (short)f2b(u.y);
        af[i][2] = (short)f2b(u.z); af[i][3] = (short)f2b(u.w);
        af[i][4] = (short)f2b(v.x); af[i][5] = (short)f2b(v.y);
        af[i][6] = (short)f2b(v.z); af[i][7] = (short)f2b(v.w);
      } else {
        af[i] = short8{0, 0, 0, 0, 0, 0, 0, 0};
      }
    }
#pragma unroll
    for (int i = 0; i < 4; ++i) bfr[i] = *(const short8*)(Bp + (size_t)i * 16 * K + k0);
#pragma unroll
    for (int mi = 0; mi < 4; ++mi)
#pragma unroll
      for (int ni = 0; ni < 4; ++ni)
        acc[mi][ni] = __builtin_amdgcn_mfma_f32_16x16x32_bf16(af[mi], bfr[ni], acc[mi][ni], 0, 0, 0);
  }
  const int rbase = bm + wr + (lane >> 4) * 4;
#pragma unroll
  for (int mi = 0; mi < 4; ++mi) {
#pragma unroll
    for (int ni = 0; ni < 4; ++ni) {
      const int col = wc + ni * 16 + l15;
      const float bv = bias[col];
#pragma unroll
      for (int r = 0; r < 4; ++r) {
        const int row = rbase + mi * 16 + r;
        const float v = acc[mi][ni][r] + bv;
        Cf[(size_t)row * Nc + col] = v;
        Cb[(size_t)row * Nc + col] = f2b(v);
      }
    }
  }
}

// ---------------- per-node attention logits: a_s/a_d[n,h] = hb[n]·w_s[l][h] ----------------
__global__ __launch_bounds__(256) void k_att2(const unsigned short* __restrict__ hb,
                                              const float* __restrict__ w_s,
                                              const float* __restrict__ w_d,
                                              float* __restrict__ a_s,
                                              float* __restrict__ a_d, int N) {
  int lane = threadIdx.x & 63;
  int n = blockIdx.x * 4 + (threadIdx.x >> 6);
  if (n >= N) return;
  unsigned hv = *(const unsigned*)(hb + (size_t)n * HID + lane * 2);
  float f0 = __uint_as_float(hv << 16);
  float f1 = __uint_as_float(hv & 0xFFFF0000u);
  float ps[4], pd[4];
#pragma unroll
  for (int h = 0; h < 4; ++h) {
    const float2 ws2 = *(const float2*)(w_s + h * HID + lane * 2);
    const float2 wd2 = *(const float2*)(w_d + h * HID + lane * 2);
    ps[h] = wsum(f0 * ws2.x + f1 * ws2.y);
    pd[h] = wsum(f0 * wd2.x + f1 * wd2.y);
  }
  if (lane == 0) {
    *(float4*)(a_s + (size_t)n * 4) = make_float4(ps[0], ps[1], ps[2], ps[3]);
    *(float4*)(a_d + (size_t)n * 4) = make_float4(pd[0], pd[1], pd[2], pd[3]);
  }
}

// ---------------- GAT aggregation in input space: agg[n, h*128+c] ----------------
// Wave per node. Softmax alphas computed once per edge (lane i <-> edge beg+i,
// valid since deg<=64 in practice), then shfl-broadcast in the gather pass.
// Gather pass: 4 edges at a time, one per 16-lane group, 16B/lane.
__global__ __launch_bounds__(256) void k_agg2(
    const int* __restrict__ rowptr, const int* __restrict__ csr,
    const unsigned short* __restrict__ hb, const float* __restrict__ a_s,
    const float* __restrict__ a_d, unsigned short* __restrict__ agg, int N) {
  int lane = threadIdx.x & 63;
  int n = blockIdx.x * 4 + (threadIdx.x >> 6);
  if (n >= N) return;
  int beg = rowptr[n], end = rowptr[n + 1];
  int deg = end - beg;
  const float4 adv = *(const float4*)(a_d + (size_t)n * 4);
  float ad[4] = {adv.x, adv.y, adv.z, adv.w};
  const int g = lane >> 4;
  const int l15 = lane & 15;
  float acc[4][8] = {};
  float f[8];
  if (deg <= 64) {
    int e = beg + lane;
    bool val = e < end;
    int s = csr[val ? e : end - 1];
    const float4 asv = *(const float4*)(a_s + (size_t)s * 4);
    float L0 = lk2(asv.x + ad[0]);
    float L1 = lk2(asv.y + ad[1]);
    float L2 = lk2(asv.z + ad[2]);
    float L3 = lk2(asv.w + ad[3]);
    float m0 = wmax(val ? L0 : -1e30f);
    float m1 = wmax(val ? L1 : -1e30f);
    float m2 = wmax(val ? L2 : -1e30f);
    float m3 = wmax(val ? L3 : -1e30f);
    float e0v = val ? exp2f(L0 - m0) : 0.f;
    float e1v = val ? exp2f(L1 - m1) : 0.f;
    float e2v = val ? exp2f(L2 - m2) : 0.f;
    float e3v = val ? exp2f(L3 - m3) : 0.f;
    float al0 = e0v / wsum(e0v);
    float al1 = e1v / wsum(e1v);
    float al2 = e2v / wsum(e2v);
    float al3 = e3v / wsum(e3v);
    int e0 = beg;
    for (; e0 + 8 <= end; e0 += 8) {
      int ea = e0 + g, eb = e0 + 4 + g;
      int sa = csr[ea], sb = csr[eb];
      uint4 ha = *(const uint4*)(hb + (size_t)sa * HID + l15 * 8);
      uint4 hbv = *(const uint4*)(hb + (size_t)sb * HID + l15 * 8);
      int ia = ea - beg, ib = eb - beg;
      float ba0 = __shfl(al0, ia, 64), ba1 = __shfl(al1, ia, 64);
      float ba2 = __shfl(al2, ia, 64), ba3 = __shfl(al3, ia, 64);
      float bb0 = __shfl(al0, ib, 64), bb1 = __shfl(al1, ib, 64);
      float bb2 = __shfl(al2, ib, 64), bb3 = __shfl(al3, ib, 64);
      unp8(ha, f);
#pragma unroll
      for (int j = 0; j < 8; ++j) {
        acc[0][j] = fmaf(ba0, f[j], acc[0][j]);
        acc[1][j] = fmaf(ba1, f[j], acc[1][j]);
        acc[2][j] = fmaf(ba2, f[j], acc[2][j]);
        acc[3][j] = fmaf(ba3, f[j], acc[3][j]);
      }
      unp8(hbv, f);
#pragma unroll
      for (int j = 0; j < 8; ++j) {
        acc[0][j] = fmaf(bb0, f[j], acc[0][j]);
        acc[1][j] = fmaf(bb1, f[j], acc[1][j]);
        acc[2][j] = fmaf(bb2, f[j], acc[2][j]);
        acc[3][j] = fmaf(bb3, f[j], acc[3][j]);
      }
    }
    for (; e0 < end; e0 += 4) {
      int ee = e0 + g;
      bool v2 = ee < end;
      int sv = csr[v2 ? ee : end - 1];
      uint4 hv = *(const uint4*)(hb + (size_t)sv * HID + l15 * 8);
      int idx = ee - beg;
      float b0 = __shfl(al0, idx & 63, 64);
      float b1 = __shfl(al1, idx & 63, 64);
      float b2 = __shfl(al2, idx & 63, 64);
      float b3 = __shfl(al3, idx & 63, 64);
      if (!v2) { b0 = b1 = b2 = b3 = 0.f; }
      unp8(hv, f);
#pragma unroll
      for (int j = 0; j < 8; ++j) {
        acc[0][j] = fmaf(b0, f[j], acc[0][j]);
        acc[1][j] = fmaf(b1, f[j], acc[1][j]);
        acc[2][j] = fmaf(b2, f[j], acc[2][j]);
        acc[3][j] = fmaf(b3, f[j], acc[3][j]);
      }
    }
  } else {
    // generic fallback (deg > 64): recompute per edge
    float m[4] = {-1e30f, -1e30f, -1e30f, -1e30f};
    for (int e = beg + lane; e < end; e += 64) {
      int s = csr[e];
      const float4 asv = *(const float4*)(a_s + (size_t)s * 4);
      m[0] = fmaxf(m[0], lk2(asv.x + ad[0]));
      m[1] = fmaxf(m[1], lk2(asv.y + ad[1]));
      m[2] = fmaxf(m[2], lk2(asv.z + ad[2]));
      m[3] = fmaxf(m[3], lk2(asv.w + ad[3]));
    }
#pragma unroll
    for (int j = 0; j < 4; ++j) m[j] = wmax(m[j]);
    float d[4] = {0.f, 0.f, 0.f, 0.f};
    for (int e = beg + lane; e < end; e += 64) {
      int s = csr[e];
      const float4 asv = *(const float4*)(a_s + (size_t)s * 4);
      d[0] += exp2f(lk2(asv.x + ad[0]) - m[0]);
      d[1] += exp2f(lk2(asv.y + ad[1]) - m[1]);
      d[2] += exp2f(lk2(asv.z + ad[2]) - m[2]);
      d[3] += exp2f(lk2(asv.w + ad[3]) - m[3]);
    }
#pragma unroll
    for (int j = 0; j < 4; ++j) d[j] = 1.f / wsum(d[j]);
    for (int e0 = beg; e0 < end; e0 += 4) {
      int ee = e0 + g;
      bool v2 = ee < end;
      int sv = csr[v2 ? ee : end - 1];
      const float4 asv = *(const float4*)(a_s + (size_t)sv * 4);
      uint4 hv = *(const uint4*)(hb + (size_t)sv * HID + l15 * 8);
      float b0 = v2 ? exp2f(lk2(asv.x + ad[0]) - m[0]) * d[0] : 0.f;
      float b1 = v2 ? exp2f(lk2(asv.y + ad[1]) - m[1]) * d[1] : 0.f;
      float b2 = v2 ? exp2f(lk2(asv.z + ad[2]) - m[2]) * d[2] : 0.f;
      float b3 = v2 ? exp2f(lk2(asv.w + ad[3]) - m[3]) * d[3] : 0.f;
      unp8(hv, f);
#pragma unroll
      for (int j = 0; j < 8; ++j) {
        acc[0][j] = fmaf(b0, f[j], acc[0][j]);
        acc[1][j] = fmaf(b1, f[j], acc[1][j]);
        acc[2][j] = fmaf(b2, f[j], acc[2][j]);
        acc[3][j] = fmaf(b3, f[j], acc[3][j]);
      }
    }
  }
  // combine the 4 edge-groups
#pragma unroll
  for (int hh = 0; hh < 4; ++hh)
#pragma unroll
    for (int j = 0; j < 8; ++j) {
      float t = acc[hh][j];
      t += __shfl_xor(t, 16, 64);
      t += __shfl_xor(t, 32, 64);
      acc[hh][j] = t;
    }
  // group g writes head g's 8 channels (static-select to keep regs)
  float o[8];
#pragma unroll
  for (int j = 0; j < 8; ++j) {
    float lo = (g & 1) ? acc[1][j] : acc[0][j];
    float hi = (g & 1) ? acc[3][j] : acc[2][j];
    o[j] = (g & 2) ? hi : lo;
  }
  uint4 pk;
  pk.x = (unsigned)f2b(o[0]) | ((unsigned)f2b(o[1]) << 16);
  pk.y = (unsigned)f2b(o[2]) | ((unsigned)f2b(o[3]) << 16);
  pk.z = (unsigned)f2b(o[4]) | ((unsigned)f2b(o[5]) << 16);
  pk.w = (unsigned)f2b(o[6]) | ((unsigned)f2b(o[7]) << 16);
  *(uint4*)(agg + (size_t)n * (HEADS * HID) + g * HID + l15 * 8) = pk;
}

// ---------------- post-agg GEMM + bias + LN + ReLU + residual (in-place h) ----------------
// C[M,128] = agg[M,512] @ Wt2^T (head-mean folded into Wt2). 4 waves x 32 rows.
__global__ __launch_bounds__(256) void k_mm2(const unsigned short* __restrict__ A,
                                             const unsigned short* __restrict__ Bt,
                                             const float* __restrict__ bias,
                                             const float* __restrict__ gamma,
                                             const float* __restrict__ beta,
                                             float* __restrict__ h,
                                             unsigned short* __restrict__ hb) {
  const int wid = threadIdx.x >> 6;
  const int lane = threadIdx.x & 63;
  const int l15 = lane & 15;
  const int lk = (lane >> 4) * 8;
  const int bm = blockIdx.x * 128;
  f32x4 acc[2][8] = {};
  const unsigned short* Ap = A + (size_t)(bm + 32 * wid + l15) * 512 + lk;
  const unsigned short* Bp = Bt + (size_t)l15 * 512 + lk;
  for (int k0 = 0; k0 < 512; k0 += 32) {
    short8 a0 = *(const short8*)(Ap + k0);
    short8 a1 = *(const short8*)(Ap + 16 * 512 + k0);
    short8 bfr[8];
#pragma unroll
    for (int ni = 0; ni < 8; ++ni)
      bfr[ni] = *(const short8*)(Bp + (size_t)ni * 16 * 512 + k0);
#pragma unroll
    for (int ni = 0; ni < 8; ++ni) {
      acc[0][ni] = __builtin_amdgcn_mfma_f32_16x16x32_bf16(a0, bfr[ni], acc[0][ni], 0, 0, 0);
      acc[1][ni] = __builtin_amdgcn_mfma_f32_16x16x32_bf16(a1, bfr[ni], acc[1][ni], 0, 0, 0);
    }
  }
  float gm[8], bt[8], bs[8];
#pragma unroll
  for (int ni = 0; ni < 8; ++ni) {
    int c = ni * 16 + l15;
    gm[ni] = gamma[c];
    bt[ni] = beta[c];
    bs[ni] = bias[c];
  }
#pragma unroll
  for (int mi = 0; mi < 2; ++mi)
#pragma unroll
    for (int ni = 0; ni < 8; ++ni)
#pragma unroll
      for (int r = 0; r < 4; ++r) acc[mi][ni][r] += bs[ni];
#pragma unroll
  for (int mi = 0; mi < 2; ++mi) {
#pragma unroll
    for (int r = 0; r < 4; ++r) {
      float s = 0.f;
#pragma unroll
      for (int ni = 0; ni < 8; ++ni) s += acc[mi][ni][r];
#pragma unroll
      for (int msk = 1; msk < 16; msk <<= 1) s += __shfl_xor(s, msk, 64);
      float mu = s * (1.f / 128.f);
      float q = 0.f;
#pragma unroll
      for (int ni = 0; ni < 8; ++ni) {
        float dd = acc[mi][ni][r] - mu;
        q += dd * dd;
      }
#pragma unroll
      for (int msk = 1; msk < 16; msk <<= 1) q += __shfl_xor(q, msk, 64);
      float rstd = rsqrtf(q * (1.f / 128.f) + LN_EPS);
      int row = bm + 32 * wid + mi * 16 + (lane >> 4) * 4 + r;
      float* hr = h + (size_t)row * HID;
      unsigned short* hbr = hb + (size_t)row * HID;
#pragma unroll
      for (int ni = 0; ni < 8; ++ni) {
        int c = ni * 16 + l15;
        float y = (acc[mi][ni][r] - mu) * rstd * gm[ni] + bt[ni];
        y = fmaxf(y, 0.f) + hr[c];
        hr[c] = y;
        hbr[c] = f2b(y);
      }
    }
  }
}

// ---------------- GCN head ----------------
__global__ __launch_bounds__(256) void k_xw(const float* __restrict__ h,
                                            const float* __restrict__ W,
                                            float* __restrict__ xw, int N) {
  int lane = threadIdx.x & 63;
  int n = blockIdx.x * 4 + (threadIdx.x >> 6);
  if (n >= N) return;
  const float* hr = h + (size_t)n * HID;
  float v = hr[lane] * W[lane] + hr[64 + lane] * W[64 + lane];
  v = wsum(v);
  if (lane == 0) xw[n] = v;
}

__global__ __launch_bounds__(256) void k_gcn(const int* __restrict__ rowptr,
                                             const int* __restrict__ csr,
                                             const float* __restrict__ xw,
                                             const float* __restrict__ dinv,
                                             const float* __restrict__ gcn_b,
                                             float* __restrict__ out, int N) {
  int n = blockIdx.x * blockDim.x + threadIdx.x;
  if (n >= N) return;
  float acc = 0.f;
  int beg = rowptr[n], end = rowptr[n + 1];
  for (int e = beg; e < end; ++e) {
    int s = csr[e];
    acc += xw[s] * dinv[s];
  }
  float z = acc * dinv[n] + gcn_b[0];
  out[n] = 1.f / (1.f + expf(-z));
}

extern "C" void kernel_launch(void* const* d_in, const int* in_sizes, int n_in,
                              void* d_out, int out_size, void* d_ws, size_t ws_size,
                              hipStream_t stream) {
  const float* x = (const float*)d_in[0];
  const int* ei = (const int*)d_in[1];
  const float* proj_W = (const float*)d_in[2];
  const float* proj_b = (const float*)d_in[3];
  const float* gat_W = (const float*)d_in[4];
  const float* gat_as = (const float*)d_in[5];
  const float* gat_ad = (const float*)d_in[6];
  const float* gat_bias = (const float*)d_in[7];
  const float* ln_g = (const float*)d_in[8];
  const float* ln_b = (const float*)d_in[9];
  const float* gcn_W = (const float*)d_in[10];
  const float* gcn_b = (const float*)d_in[11];
  float* out = (float*)d_out;

  const int N = in_sizes[0] / INDIM;  // 40000
  const int E = in_sizes[1] / 2;      // 320000
  const int TOT = E + N;

  size_t off = 0;
  auto alloc = [&](size_t bytes) {
    void* p = (char*)d_ws + off;
    off += (bytes + 255) & ~(size_t)255;
    return p;
  };
  float* h = (float*)alloc((size_t)MPAD * HID * 4);
  unsigned short* hb = (unsigned short*)alloc((size_t)MPAD * HID * 2);
  unsigned short* agg = (unsigned short*)alloc((size_t)MPAD * HEADS * HID * 2);
  unsigned short* WtP = (unsigned short*)alloc((size_t)HID * INDIM * 2);
  unsigned short* Wt2 = (unsigned short*)alloc((size_t)NGAT * HID * HEADS * HID * 2);
  float* w_s = (float*)alloc((size_t)NGAT * HEADS * HID * 4);
  float* w_d = (float*)alloc((size_t)NGAT * HEADS * HID * 4);
  float* a_s = (float*)alloc((size_t)N * HEADS * 4);
  float* a_d = (float*)alloc((size_t)N * HEADS * 4);
  int* deg = (int*)alloc((size_t)N * 4);
  int* rowptr = (int*)alloc((size_t)(N + 1) * 4);
  int* cursor = (int*)alloc((size_t)N * 4);
  int* csr = (int*)alloc((size_t)TOT * 4);
  int* bsums = (int*)alloc(1024);
  float* dinv = (float*)alloc((size_t)N * 4);
  float* xw = (float*)alloc((size_t)N * 4);
  (void)ws_size;

  const int NBLK = (N + 255) / 256;
  const int EBLK = (TOT + 255) / 256;
  const int WBLK = (N + 3) / 4;

  // CSR build
  hipMemsetAsync(deg, 0, (size_t)N * 4, stream);
  k_deg<<<EBLK, 256, 0, stream>>>(ei, E, N, deg);
  k_scan1<<<NBLK, 256, 0, stream>>>(deg, N, bsums);
  k_scan2<<<1, 1, 0, stream>>>(bsums, NBLK, rowptr, N);
  k_scan3<<<NBLK, 256, 0, stream>>>(deg, N, bsums, rowptr, cursor, dinv);
  k_fill<<<EBLK, 256, 0, stream>>>(ei, E, N, cursor, csr);

  // weight prep
  k_wt<<<(INDIM * HID + 255) / 256, 256, 0, stream>>>(proj_W, WtP, INDIM, HID);
  k_wt2<<<(NGAT * HID * HEADS * HID + 255) / 256, 256, 0, stream>>>(gat_W, Wt2);
  k_wvec<<<(NGAT * HEADS * HID + 3) / 4, 256, 0, stream>>>(gat_W, gat_as, gat_ad, w_s, w_d);

  // zero agg pad rows (keeps tail-block LN inputs deterministic/finite)
  hipMemsetAsync(agg + (size_t)N * HEADS * HID, 0,
                 (size_t)(MPAD - N) * HEADS * HID * 2, stream);

  // projection: h = x @ proj_W + proj_b
  k_mm<INDIM><<<dim3(MPAD / 128, 1), 256, 0, stream>>>(x, WtP, proj_b, h, hb, HID, N);

  for (int i = 0; i < NGAT; ++i) {
    k_att2<<<WBLK, 256, 0, stream>>>(hb, w_s + (size_t)i * HEADS * HID,
                                     w_d + (size_t)i * HEADS * HID, a_s, a_d, N);
    k_agg2<<<WBLK, 256, 0, stream>>>(rowptr, csr, hb, a_s, a_d, agg, N);
    k_mm2<<<MPAD / 128, 256, 0, stream>>>(agg, Wt2 + (size_t)i * HID * HEADS * HID,
                                          gat_bias + (size_t)i * HID,
                                          ln_g + (size_t)i * HID,
                                          ln_b + (size_t)i * HID, h, hb);
  }

  // GCN head
  k_xw<<<WBLK, 256, 0, stream>>>(h, gcn_W, xw, N);
  k_gcn<<<NBLK, 256, 0, stream>>>(rowptr, csr, xw, dinv, gcn_b, out, N);
}

// Round 6
// 484.484 us; speedup vs baseline: 2.1498x; 2.1498x over previous
//
#include <hip/hip_runtime.h>
#include <math.h>

#define INDIM 256
#define HID 128
#define HEADS 4
#define NGAT 3
#define LN_EPS 1e-5f
#define SLOPE 0.2f
#define MPAD 40064  // 313 * 128
#define LOG2E 1.4426950408889634f

typedef __attribute__((ext_vector_type(8))) short short8;
typedef __attribute__((ext_vector_type(4))) float f32x4;

__device__ inline float wsum(float v) {
#pragma unroll
  for (int m = 1; m < 64; m <<= 1) v += __shfl_xor(v, m, 64);
  return v;
}
__device__ inline float wmax(float v) {
#pragma unroll
  for (int m = 1; m < 64; m <<= 1) v = fmaxf(v, __shfl_xor(v, m, 64));
  return v;
}
// leaky_relu then scale to exp2 domain
__device__ inline float lk2(float v) { return fmaxf(v, SLOPE * v) * LOG2E; }
// static-select (i must be wave-group index; broadcast BEFORE select!)
__device__ inline float sel4(float a0, float a1, float a2, float a3, int i) {
  float lo = (i & 1) ? a1 : a0;
  float hi = (i & 1) ? a3 : a2;
  return (i & 2) ? hi : lo;
}

__device__ inline unsigned short f2b(float f) {
  unsigned u = __float_as_uint(f);
  unsigned r = (u + 0x7FFFu + ((u >> 16) & 1u)) >> 16;
  return (unsigned short)r;
}
__device__ inline void unp8(const uint4 v, float f[8]) {
  f[0] = __uint_as_float(v.x << 16);
  f[1] = __uint_as_float(v.x & 0xFFFF0000u);
  f[2] = __uint_as_float(v.y << 16);
  f[3] = __uint_as_float(v.y & 0xFFFF0000u);
  f[4] = __uint_as_float(v.z << 16);
  f[5] = __uint_as_float(v.z & 0xFFFF0000u);
  f[6] = __uint_as_float(v.w << 16);
  f[7] = __uint_as_float(v.w & 0xFFFF0000u);
}

// ---------------- CSR construction ----------------
__global__ void k_deg(const int* __restrict__ ei, int E, int N, int* __restrict__ deg) {
  int e = blockIdx.x * blockDim.x + threadIdx.x;
  if (e >= E + N) return;
  int dst = (e < E) ? ei[E + e] : (e - E);
  atomicAdd(&deg[dst], 1);
}

__global__ void k_scan1(const int* __restrict__ deg, int N, int* __restrict__ bsums) {
  __shared__ int s[256];
  int gid = blockIdx.x * 256 + threadIdx.x;
  s[threadIdx.x] = (gid < N) ? deg[gid] : 0;
  __syncthreads();
  for (int off = 128; off > 0; off >>= 1) {
    if (threadIdx.x < off) s[threadIdx.x] += s[threadIdx.x + off];
    __syncthreads();
  }
  if (threadIdx.x == 0) bsums[blockIdx.x] = s[0];
}

__global__ void k_scan2(int* __restrict__ bsums, int nblk, int* __restrict__ rowptr, int N) {
  if (threadIdx.x == 0 && blockIdx.x == 0) {
    int run = 0;
    for (int i = 0; i < nblk; ++i) { int t = bsums[i]; bsums[i] = run; run += t; }
    rowptr[N] = run;
  }
}

__global__ void k_scan3(const int* __restrict__ deg, int N, const int* __restrict__ bsums,
                        int* __restrict__ rowptr, int* __restrict__ cursor,
                        float* __restrict__ dinv) {
  __shared__ int s[256];
  int gid = blockIdx.x * 256 + threadIdx.x;
  int v = (gid < N) ? deg[gid] : 0;
  s[threadIdx.x] = v;
  __syncthreads();
  for (int off = 1; off < 256; off <<= 1) {
    int t = (threadIdx.x >= off) ? s[threadIdx.x - off] : 0;
    __syncthreads();
    s[threadIdx.x] += t;
    __syncthreads();
  }
  if (gid < N) {
    int ex = bsums[blockIdx.x] + s[threadIdx.x] - v;
    rowptr[gid] = ex;
    cursor[gid] = ex;
    dinv[gid] = rsqrtf((float)v);
  }
}

__global__ void k_fill(const int* __restrict__ ei, int E, int N,
                       int* __restrict__ cursor, int* __restrict__ csr) {
  int e = blockIdx.x * blockDim.x + threadIdx.x;
  if (e >= E + N) return;
  int src, dst;
  if (e < E) { src = ei[e]; dst = ei[E + e]; } else { src = dst = e - E; }
  int pos = atomicAdd(&cursor[dst], 1);
  csr[pos] = src;
}

// ---------------- weight prep ----------------
// proj_W [INDIM][HID] -> WtP [HID][INDIM] bf16
__global__ void k_wt(const float* __restrict__ W, unsigned short* __restrict__ Wt,
                     int K, int Nc) {
  int idx = blockIdx.x * 256 + threadIdx.x;
  if (idx >= K * Nc) return;
  int k = idx / Nc, n = idx % Nc;
  Wt[n * K + k] = f2b(W[idx]);
}

// gat_W [NGAT][128 k][512 (h*128+c)] -> Wt2 [NGAT][128 c][512 (h*128+k)] * 0.25
__global__ void k_wt2(const float* __restrict__ W, unsigned short* __restrict__ Wt) {
  int idx = blockIdx.x * 256 + threadIdx.x;
  if (idx >= NGAT * HID * HEADS * HID) return;
  int l = idx / (HID * HEADS * HID);
  int rem = idx - l * HID * HEADS * HID;
  int k = rem / (HEADS * HID);
  int col = rem % (HEADS * HID);
  int hh = col >> 7, c = col & 127;
  Wt[(size_t)l * (HID * HEADS * HID) + (size_t)c * (HEADS * HID) + hh * HID + k] =
      f2b(W[idx] * 0.25f);
}

// w_s[l][h][k] = sum_c gat_W[l][k][h*128+c] * att_src[l][h][c]  (and w_d)
__global__ void k_wvec(const float* __restrict__ W, const float* __restrict__ atts,
                       const float* __restrict__ attd, float* __restrict__ w_s,
                       float* __restrict__ w_d) {
  int lane = threadIdx.x & 63;
  int idx = blockIdx.x * 4 + (threadIdx.x >> 6);
  if (idx >= NGAT * HEADS * HID) return;
  int l = idx / (HEADS * HID);
  int rem = idx - l * (HEADS * HID);
  int hh = rem >> 7, k = rem & 127;
  const float2 w2 = *(const float2*)(W + ((size_t)(l * HID + k)) * (HEADS * HID) +
                                     hh * HID + lane * 2);
  const float2 s2 = *(const float2*)(atts + (size_t)(l * HEADS + hh) * HID + lane * 2);
  const float2 d2 = *(const float2*)(attd + (size_t)(l * HEADS + hh) * HID + lane * 2);
  float ps = w2.x * s2.x + w2.y * s2.y;
  float pd = w2.x * d2.x + w2.y * d2.y;
  ps = wsum(ps);
  pd = wsum(pd);
  if (lane == 0) { w_s[idx] = ps; w_d[idx] = pd; }
}

// ---------------- projection GEMM: h = x(fp32) @ WtP^T + b ----------------
// 64-row blocks (4 waves x 16 rows x 128 cols), grid = MPAD/64.
template <int K>
__global__ __launch_bounds__(256) void k_mm(const float* __restrict__ Af,
                                            const unsigned short* __restrict__ Bt,
                                            const float* __restrict__ bias,
                                            float* __restrict__ Cf,
                                            unsigned short* __restrict__ Cb,
                                            int Mreal) {
  const int wid = threadIdx.x >> 6;
  const int lane = threadIdx.x & 63;
  const int l15 = lane & 15;
  const int lk = (lane >> 4) * 8;
  const int row0 = blockIdx.x * 64 + wid * 16;
  f32x4 acc[8] = {};
  const unsigned short* Bp = Bt + (size_t)l15 * K + lk;
  const int arow = row0 + l15;
  for (int k0 = 0; k0 < K; k0 += 32) {
    short8 af;
    if (arow < Mreal) {
      const float* ap = Af + (size_t)arow * K + lk + k0;
      float4 u = *(const float4*)ap;
      float4 v = *(const float4*)(ap + 4);
      af[0] = (short)f2b(u.x); af[1] = (short)f2b(u.y);
      af[2] = (short)f2b(u.z); af[3] = (short)f2b(u.w);
      af[4] = (short)f2b(v.x); af[5] = (short)f2b(v.y);
      af[6] = (short)f2b(v.z); af[7] = (short)f2b(v.w);
    } else {
      af = short8{0, 0, 0, 0, 0, 0, 0, 0};
    }
    short8 bfr[8];
#pragma unroll
    for (int ni = 0; ni < 8; ++ni)
      bfr[ni] = *(const short8*)(Bp + (size_t)ni * 16 * K + k0);
#pragma unroll
    for (int ni = 0; ni < 8; ++ni)
      acc[ni] = __builtin_amdgcn_mfma_f32_16x16x32_bf16(af, bfr[ni], acc[ni], 0, 0, 0);
  }
#pragma unroll
  for (int ni = 0; ni < 8; ++ni) {
    const int col = ni * 16 + l15;
    const float bv = bias[col];
#pragma unroll
    for (int r = 0; r < 4; ++r) {
      const int row = row0 + (lane >> 4) * 4 + r;
      const float v = acc[ni][r] + bv;
      Cf[(size_t)row * HID + col] = v;
      Cb[(size_t)row * HID + col] = f2b(v);
    }
  }
}

// ---------------- per-node attention logits: a_s/a_d[n,h] = hb[n]·w_s[l][h] ----------------
__global__ __launch_bounds__(256) void k_att2(const unsigned short* __restrict__ hb,
                                              const float* __restrict__ w_s,
                                              const float* __restrict__ w_d,
                                              float* __restrict__ a_s,
                                              float* __restrict__ a_d, int N) {
  int lane = threadIdx.x & 63;
  int n = blockIdx.x * 4 + (threadIdx.x >> 6);
  if (n >= N) return;
  unsigned hv = *(const unsigned*)(hb + (size_t)n * HID + lane * 2);
  float f0 = __uint_as_float(hv << 16);
  float f1 = __uint_as_float(hv & 0xFFFF0000u);
  float ps[4], pd[4];
#pragma unroll
  for (int h = 0; h < 4; ++h) {
    const float2 ws2 = *(const float2*)(w_s + h * HID + lane * 2);
    const float2 wd2 = *(const float2*)(w_d + h * HID + lane * 2);
    ps[h] = wsum(f0 * ws2.x + f1 * ws2.y);
    pd[h] = wsum(f0 * wd2.x + f1 * wd2.y);
  }
  if (lane == 0) {
    *(float4*)(a_s + (size_t)n * 4) = make_float4(ps[0], ps[1], ps[2], ps[3]);
    *(float4*)(a_d + (size_t)n * 4) = make_float4(pd[0], pd[1], pd[2], pd[3]);
  }
}

// ---------------- GAT aggregation in input space: agg[n, h*128+c] ----------------
// Wave per node. Lane (g,l15) owns head g, channels l15*8..+7 of gathered h.
// Per edge: ONE 256B row load (addr depends only on l15; 4-way broadcast across
// head-groups). Alphas: broadcast all 4 heads' alpha from the edge's prologue
// lane, THEN select head g (shfl before sel4 — lane i's registers are indexed
// by lane i's own group, so selecting first reads the wrong head).
__global__ __launch_bounds__(256) void k_agg2(
    const int* __restrict__ rowptr, const int* __restrict__ csr,
    const unsigned short* __restrict__ hb, const float* __restrict__ a_s,
    const float* __restrict__ a_d, unsigned short* __restrict__ agg, int N) {
  int lane = threadIdx.x & 63;
  int n = blockIdx.x * 4 + (threadIdx.x >> 6);
  if (n >= N) return;
  int beg = rowptr[n], end = rowptr[n + 1];
  int deg = end - beg;
  const float4 adv = *(const float4*)(a_d + (size_t)n * 4);
  const int g = lane >> 4;
  const int l15 = lane & 15;
  const unsigned short* hbase = hb + l15 * 8;
  float acc[8] = {};
  float f[8];
  if (deg <= 64) {
    // prologue: lane i <-> edge beg+i; alphas for all 4 heads kept per-lane
    int e = beg + lane;
    bool val = e < end;
    int s = csr[val ? e : end - 1];
    const float4 asv = *(const float4*)(a_s + (size_t)s * 4);
    float L0 = lk2(asv.x + adv.x);
    float L1 = lk2(asv.y + adv.y);
    float L2 = lk2(asv.z + adv.z);
    float L3 = lk2(asv.w + adv.w);
    float m0 = wmax(val ? L0 : -3e38f);
    float m1 = wmax(val ? L1 : -3e38f);
    float m2 = wmax(val ? L2 : -3e38f);
    float m3 = wmax(val ? L3 : -3e38f);
    float e0 = val ? exp2f(L0 - m0) : 0.f;
    float e1 = val ? exp2f(L1 - m1) : 0.f;
    float e2 = val ? exp2f(L2 - m2) : 0.f;
    float e3 = val ? exp2f(L3 - m3) : 0.f;
    float al0 = e0 / wsum(e0);
    float al1 = e1 / wsum(e1);
    float al2 = e2 / wsum(e2);
    float al3 = e3 / wsum(e3);
    int i = 0;
    for (; i + 2 <= deg; i += 2) {
      int s0 = __shfl(s, i, 64);
      int s1 = __shfl(s, i + 1, 64);
      float a00 = __shfl(al0, i, 64), a01 = __shfl(al1, i, 64);
      float a02 = __shfl(al2, i, 64), a03 = __shfl(al3, i, 64);
      float a10 = __shfl(al0, i + 1, 64), a11 = __shfl(al1, i + 1, 64);
      float a12 = __shfl(al2, i + 1, 64), a13 = __shfl(al3, i + 1, 64);
      uint4 h0 = *(const uint4*)(hbase + (size_t)s0 * HID);
      uint4 h1 = *(const uint4*)(hbase + (size_t)s1 * HID);
      float b0 = sel4(a00, a01, a02, a03, g);
      float b1 = sel4(a10, a11, a12, a13, g);
      unp8(h0, f);
#pragma unroll
      for (int j = 0; j < 8; ++j) acc[j] = fmaf(b0, f[j], acc[j]);
      unp8(h1, f);
#pragma unroll
      for (int j = 0; j < 8; ++j) acc[j] = fmaf(b1, f[j], acc[j]);
    }
    if (i < deg) {
      int s0 = __shfl(s, i, 64);
      float a00 = __shfl(al0, i, 64), a01 = __shfl(al1, i, 64);
      float a02 = __shfl(al2, i, 64), a03 = __shfl(al3, i, 64);
      uint4 h0 = *(const uint4*)(hbase + (size_t)s0 * HID);
      float b0 = sel4(a00, a01, a02, a03, g);
      unp8(h0, f);
#pragma unroll
      for (int j = 0; j < 8; ++j) acc[j] = fmaf(b0, f[j], acc[j]);
    }
  } else {
    // rare fallback: two passes for m/d, then 64-edge strips
    float m0 = -3e38f, m1 = -3e38f, m2 = -3e38f, m3 = -3e38f;
    for (int e = beg + lane; e < end; e += 64) {
      int s = csr[e];
      const float4 asv = *(const float4*)(a_s + (size_t)s * 4);
      m0 = fmaxf(m0, lk2(asv.x + adv.x));
      m1 = fmaxf(m1, lk2(asv.y + adv.y));
      m2 = fmaxf(m2, lk2(asv.z + adv.z));
      m3 = fmaxf(m3, lk2(asv.w + adv.w));
    }
    m0 = wmax(m0); m1 = wmax(m1); m2 = wmax(m2); m3 = wmax(m3);
    float d0 = 0.f, d1 = 0.f, d2 = 0.f, d3 = 0.f;
    for (int e = beg + lane; e < end; e += 64) {
      int s = csr[e];
      const float4 asv = *(const float4*)(a_s + (size_t)s * 4);
      d0 += exp2f(lk2(asv.x + adv.x) - m0);
      d1 += exp2f(lk2(asv.y + adv.y) - m1);
      d2 += exp2f(lk2(asv.z + adv.z) - m2);
      d3 += exp2f(lk2(asv.w + adv.w) - m3);
    }
    float r0 = 1.f / wsum(d0);
    float r1 = 1.f / wsum(d1);
    float r2 = 1.f / wsum(d2);
    float r3 = 1.f / wsum(d3);
    for (int sb = beg; sb < end; sb += 64) {
      int e = sb + lane;
      bool val = e < end;
      int s = csr[val ? e : end - 1];
      const float4 asv = *(const float4*)(a_s + (size_t)s * 4);
      float q0 = val ? exp2f(lk2(asv.x + adv.x) - m0) * r0 : 0.f;
      float q1 = val ? exp2f(lk2(asv.y + adv.y) - m1) * r1 : 0.f;
      float q2 = val ? exp2f(lk2(asv.z + adv.z) - m2) * r2 : 0.f;
      float q3 = val ? exp2f(lk2(asv.w + adv.w) - m3) * r3 : 0.f;
      int cnt = min(64, end - sb);
      for (int i = 0; i < cnt; ++i) {
        int si = __shfl(s, i, 64);
        float c0 = __shfl(q0, i, 64), c1 = __shfl(q1, i, 64);
        float c2 = __shfl(q2, i, 64), c3 = __shfl(q3, i, 64);
        uint4 hv = *(const uint4*)(hbase + (size_t)si * HID);
        float bi = sel4(c0, c1, c2, c3, g);
        unp8(hv, f);
#pragma unroll
        for (int j = 0; j < 8; ++j) acc[j] = fmaf(bi, f[j], acc[j]);
      }
    }
  }
  uint4 pk;
  pk.x = (unsigned)f2b(acc[0]) | ((unsigned)f2b(acc[1]) << 16);
  pk.y = (unsigned)f2b(acc[2]) | ((unsigned)f2b(acc[3]) << 16);
  pk.z = (unsigned)f2b(acc[4]) | ((unsigned)f2b(acc[5]) << 16);
  pk.w = (unsigned)f2b(acc[6]) | ((unsigned)f2b(acc[7]) << 16);
  *(uint4*)(agg + (size_t)n * (HEADS * HID) + g * HID + l15 * 8) = pk;
}

// ---------------- post-agg GEMM + bias + LN + ReLU + residual (in-place h) ----------------
// C[M,128] = agg[M,512] @ Wt2^T. 64-row blocks (4 waves x 16 rows), grid = MPAD/64.
__global__ __launch_bounds__(256) void k_mm2(const unsigned short* __restrict__ A,
                                             const unsigned short* __restrict__ Bt,
                                             const float* __restrict__ bias,
                                             const float* __restrict__ gamma,
                                             const float* __restrict__ beta,
                                             float* __restrict__ h,
                                             unsigned short* __restrict__ hb) {
  const int wid = threadIdx.x >> 6;
  const int lane = threadIdx.x & 63;
  const int l15 = lane & 15;
  const int lk = (lane >> 4) * 8;
  const int row0 = blockIdx.x * 64 + wid * 16;
  f32x4 acc[8] = {};
  const unsigned short* Ap = A + (size_t)(row0 + l15) * 512 + lk;
  const unsigned short* Bp = Bt + (size_t)l15 * 512 + lk;
  for (int k0 = 0; k0 < 512; k0 += 32) {
    short8 a0 = *(const short8*)(Ap + k0);
    short8 bfr[8];
#pragma unroll
    for (int ni = 0; ni < 8; ++ni)
      bfr[ni] = *(const short8*)(Bp + (size_t)ni * 16 * 512 + k0);
#pragma unroll
    for (int ni = 0; ni < 8; ++ni)
      acc[ni] = __builtin_amdgcn_mfma_f32_16x16x32_bf16(a0, bfr[ni], acc[ni], 0, 0, 0);
  }
  float gm[8], bt8[8], bs[8];
#pragma unroll
  for (int ni = 0; ni < 8; ++ni) {
    int c = ni * 16 + l15;
    gm[ni] = gamma[c];
    bt8[ni] = beta[c];
    bs[ni] = bias[c];
  }
#pragma unroll
  for (int ni = 0; ni < 8; ++ni)
#pragma unroll
    for (int r = 0; r < 4; ++r) acc[ni][r] += bs[ni];
#pragma unroll
  for (int r = 0; r < 4; ++r) {
    float s = 0.f;
#pragma unroll
    for (int ni = 0; ni < 8; ++ni) s += acc[ni][r];
#pragma unroll
    for (int msk = 1; msk < 16; msk <<= 1) s += __shfl_xor(s, msk, 64);
    float mu = s * (1.f / 128.f);
    float q = 0.f;
#pragma unroll
    for (int ni = 0; ni < 8; ++ni) {
      float dd = acc[ni][r] - mu;
      q += dd * dd;
    }
#pragma unroll
    for (int msk = 1; msk < 16; msk <<= 1) q += __shfl_xor(q, msk, 64);
    float rstd = rsqrtf(q * (1.f / 128.f) + LN_EPS);
    int row = row0 + (lane >> 4) * 4 + r;
    float* hr = h + (size_t)row * HID;
    unsigned short* hbr = hb + (size_t)row * HID;
#pragma unroll
    for (int ni = 0; ni < 8; ++ni) {
      int c = ni * 16 + l15;
      float y = (acc[ni][r] - mu) * rstd * gm[ni] + bt8[ni];
      y = fmaxf(y, 0.f) + hr[c];
      hr[c] = y;
      hbr[c] = f2b(y);
    }
  }
}

// ---------------- GCN head ----------------
__global__ __launch_bounds__(256) void k_xw(const float* __restrict__ h,
                                            const float* __restrict__ W,
                                            float* __restrict__ xw, int N) {
  int lane = threadIdx.x & 63;
  int n = blockIdx.x * 4 + (threadIdx.x >> 6);
  if (n >= N) return;
  const float* hr = h + (size_t)n * HID;
  float v = hr[lane] * W[lane] + hr[64 + lane] * W[64 + lane];
  v = wsum(v);
  if (lane == 0) xw[n] = v;
}

__global__ __launch_bounds__(256) void k_gcn(const int* __restrict__ rowptr,
                                             const int* __restrict__ csr,
                                             const float* __restrict__ xw,
                                             const float* __restrict__ dinv,
                                             const float* __restrict__ gcn_b,
                                             float* __restrict__ out, int N) {
  int n = blockIdx.x * blockDim.x + threadIdx.x;
  if (n >= N) return;
  float acc = 0.f;
  int beg = rowptr[n], end = rowptr[n + 1];
  for (int e = beg; e < end; ++e) {
    int s = csr[e];
    acc += xw[s] * dinv[s];
  }
  float z = acc * dinv[n] + gcn_b[0];
  out[n] = 1.f / (1.f + expf(-z));
}

extern "C" void kernel_launch(void* const* d_in, const int* in_sizes, int n_in,
                              void* d_out, int out_size, void* d_ws, size_t ws_size,
                              hipStream_t stream) {
  const float* x = (const float*)d_in[0];
  const int* ei = (const int*)d_in[1];
  const float* proj_W = (const float*)d_in[2];
  const float* proj_b = (const float*)d_in[3];
  const float* gat_W = (const float*)d_in[4];
  const float* gat_as = (const float*)d_in[5];
  const float* gat_ad = (const float*)d_in[6];
  const float* gat_bias = (const float*)d_in[7];
  const float* ln_g = (const float*)d_in[8];
  const float* ln_b = (const float*)d_in[9];
  const float* gcn_W = (const float*)d_in[10];
  const float* gcn_b = (const float*)d_in[11];
  float* out = (float*)d_out;

  const int N = in_sizes[0] / INDIM;  // 40000
  const int E = in_sizes[1] / 2;      // 320000
  const int TOT = E + N;

  size_t off = 0;
  auto alloc = [&](size_t bytes) {
    void* p = (char*)d_ws + off;
    off += (bytes + 255) & ~(size_t)255;
    return p;
  };
  float* h = (float*)alloc((size_t)MPAD * HID * 4);
  unsigned short* hb = (unsigned short*)alloc((size_t)MPAD * HID * 2);
  unsigned short* agg = (unsigned short*)alloc((size_t)MPAD * HEADS * HID * 2);
  unsigned short* WtP = (unsigned short*)alloc((size_t)HID * INDIM * 2);
  unsigned short* Wt2 = (unsigned short*)alloc((size_t)NGAT * HID * HEADS * HID * 2);
  float* w_s = (float*)alloc((size_t)NGAT * HEADS * HID * 4);
  float* w_d = (float*)alloc((size_t)NGAT * HEADS * HID * 4);
  float* a_s = (float*)alloc((size_t)N * HEADS * 4);
  float* a_d = (float*)alloc((size_t)N * HEADS * 4);
  int* deg = (int*)alloc((size_t)N * 4);
  int* rowptr = (int*)alloc((size_t)(N + 1) * 4);
  int* cursor = (int*)alloc((size_t)N * 4);
  int* csr = (int*)alloc((size_t)TOT * 4);
  int* bsums = (int*)alloc(1024);
  float* dinv = (float*)alloc((size_t)N * 4);
  float* xw = (float*)alloc((size_t)N * 4);
  (void)ws_size;

  const int NBLK = (N + 255) / 256;
  const int EBLK = (TOT + 255) / 256;
  const int WBLK = (N + 3) / 4;

  // CSR build
  hipMemsetAsync(deg, 0, (size_t)N * 4, stream);
  k_deg<<<EBLK, 256, 0, stream>>>(ei, E, N, deg);
  k_scan1<<<NBLK, 256, 0, stream>>>(deg, N, bsums);
  k_scan2<<<1, 1, 0, stream>>>(bsums, NBLK, rowptr, N);
  k_scan3<<<NBLK, 256, 0, stream>>>(deg, N, bsums, rowptr, cursor, dinv);
  k_fill<<<EBLK, 256, 0, stream>>>(ei, E, N, cursor, csr);

  // weight prep
  k_wt<<<(INDIM * HID + 255) / 256, 256, 0, stream>>>(proj_W, WtP, INDIM, HID);
  k_wt2<<<(NGAT * HID * HEADS * HID + 255) / 256, 256, 0, stream>>>(gat_W, Wt2);
  k_wvec<<<(NGAT * HEADS * HID + 3) / 4, 256, 0, stream>>>(gat_W, gat_as, gat_ad, w_s, w_d);

  // zero agg pad rows (k_mm2 reads them; keeps LN inputs finite)
  hipMemsetAsync(agg + (size_t)N * HEADS * HID, 0,
                 (size_t)(MPAD - N) * HEADS * HID * 2, stream);

  // projection: h = x @ proj_W + proj_b
  k_mm<INDIM><<<MPAD / 64, 256, 0, stream>>>(x, WtP, proj_b, h, hb, N);

  for (int i = 0; i < NGAT; ++i) {
    k_att2<<<WBLK, 256, 0, stream>>>(hb, w_s + (size_t)i * HEADS * HID,
                                     w_d + (size_t)i * HEADS * HID, a_s, a_d, N);
    k_agg2<<<WBLK, 256, 0, stream>>>(rowptr, csr, hb, a_s, a_d, agg, N);
    k_mm2<<<MPAD / 64, 256, 0, stream>>>(agg, Wt2 + (size_t)i * HID * HEADS * HID,
                                         gat_bias + (size_t)i * HID,
                                         ln_g + (size_t)i * HID,
                                         ln_b + (size_t)i * HID, h, hb);
  }

  // GCN head
  k_xw<<<WBLK, 256, 0, stream>>>(h, gcn_W, xw, N);
  k_gcn<<<NBLK, 256, 0, stream>>>(rowptr, csr, xw, dinv, gcn_b, out, N);
}

// Round 7
// 339.232 us; speedup vs baseline: 3.0703x; 1.4282x over previous
//
#include <hip/hip_runtime.h>
#include <math.h>

#define INDIM 256
#define HID 128
#define HEADS 4
#define NGAT 3
#define LN_EPS 1e-5f
#define SLOPE 0.2f
#define MPAD 40064  // 313 * 128; N=40000 is divisible by 16
#define LOG2E 1.4426950408889634f

typedef __attribute__((ext_vector_type(8))) short short8;
typedef __attribute__((ext_vector_type(4))) float f32x4;

__device__ inline float wsum(float v) {
#pragma unroll
  for (int m = 1; m < 64; m <<= 1) v += __shfl_xor(v, m, 64);
  return v;
}
__device__ inline float wmax(float v) {
#pragma unroll
  for (int m = 1; m < 64; m <<= 1) v = fmaxf(v, __shfl_xor(v, m, 64));
  return v;
}
// leaky_relu then scale to exp2 domain
__device__ inline float lk2(float v) { return fmaxf(v, SLOPE * v) * LOG2E; }
// static-select (broadcast BEFORE select — see round-5 lesson)
__device__ inline float sel4(float a0, float a1, float a2, float a3, int i) {
  float lo = (i & 1) ? a1 : a0;
  float hi = (i & 1) ? a3 : a2;
  return (i & 2) ? hi : lo;
}

__device__ inline unsigned short f2b(float f) {
  unsigned u = __float_as_uint(f);
  unsigned r = (u + 0x7FFFu + ((u >> 16) & 1u)) >> 16;
  return (unsigned short)r;
}
__device__ inline void unp8(const uint4 v, float f[8]) {
  f[0] = __uint_as_float(v.x << 16);
  f[1] = __uint_as_float(v.x & 0xFFFF0000u);
  f[2] = __uint_as_float(v.y << 16);
  f[3] = __uint_as_float(v.y & 0xFFFF0000u);
  f[4] = __uint_as_float(v.z << 16);
  f[5] = __uint_as_float(v.z & 0xFFFF0000u);
  f[6] = __uint_as_float(v.w << 16);
  f[7] = __uint_as_float(v.w & 0xFFFF0000u);
}

// MFMA fragment layout index: element (row,k) of a [rows][K] bf16 matrix.
// Block = 16 rows x 32 k, stored as [64 lanes][8 elems]; lane = ((k>>3)&3)*16
// + (row&15), so a wave-load at base+lane*16B yields exactly the A/B fragment.
__device__ __host__ inline size_t fidx(int row, int k, int K) {
  return ((size_t)(row >> 4) * (K >> 5) + (k >> 5)) * 512 +
         ((((k >> 3) & 3) * 16 + (row & 15)) << 3) + (k & 7);
}

// ---------------- CSR construction ----------------
__global__ void k_deg(const int* __restrict__ ei, int E, int N, int* __restrict__ deg) {
  int e = blockIdx.x * blockDim.x + threadIdx.x;
  if (e >= E + N) return;
  int dst = (e < E) ? ei[E + e] : (e - E);
  atomicAdd(&deg[dst], 1);
}

__global__ void k_scan1(const int* __restrict__ deg, int N, int* __restrict__ bsums) {
  __shared__ int s[256];
  int gid = blockIdx.x * 256 + threadIdx.x;
  s[threadIdx.x] = (gid < N) ? deg[gid] : 0;
  __syncthreads();
  for (int off = 128; off > 0; off >>= 1) {
    if (threadIdx.x < off) s[threadIdx.x] += s[threadIdx.x + off];
    __syncthreads();
  }
  if (threadIdx.x == 0) bsums[blockIdx.x] = s[0];
}

__global__ void k_scan2(int* __restrict__ bsums, int nblk, int* __restrict__ rowptr, int N) {
  if (threadIdx.x == 0 && blockIdx.x == 0) {
    int run = 0;
    for (int i = 0; i < nblk; ++i) { int t = bsums[i]; bsums[i] = run; run += t; }
    rowptr[N] = run;
  }
}

__global__ void k_scan3(const int* __restrict__ deg, int N, const int* __restrict__ bsums,
                        int* __restrict__ rowptr, int* __restrict__ cursor,
                        float* __restrict__ dinv) {
  __shared__ int s[256];
  int gid = blockIdx.x * 256 + threadIdx.x;
  int v = (gid < N) ? deg[gid] : 0;
  s[threadIdx.x] = v;
  __syncthreads();
  for (int off = 1; off < 256; off <<= 1) {
    int t = (threadIdx.x >= off) ? s[threadIdx.x - off] : 0;
    __syncthreads();
    s[threadIdx.x] += t;
    __syncthreads();
  }
  if (gid < N) {
    int ex = bsums[blockIdx.x] + s[threadIdx.x] - v;
    rowptr[gid] = ex;
    cursor[gid] = ex;
    dinv[gid] = rsqrtf((float)v);
  }
}

__global__ void k_fill(const int* __restrict__ ei, int E, int N,
                       int* __restrict__ cursor, int* __restrict__ csr) {
  int e = blockIdx.x * blockDim.x + threadIdx.x;
  if (e >= E + N) return;
  int src, dst;
  if (e < E) { src = ei[e]; dst = ei[E + e]; } else { src = dst = e - E; }
  int pos = atomicAdd(&cursor[dst], 1);
  csr[pos] = src;
}

// ---------------- weight/input prep (fragment layouts) ----------------
// proj_W [256 k][128 c] -> WtPF fragment layout (col=c, K=256)
__global__ void k_wtp(const float* __restrict__ W, unsigned short* __restrict__ Wt) {
  int idx = blockIdx.x * 256 + threadIdx.x;
  if (idx >= INDIM * HID) return;
  int k = idx >> 7, c = idx & 127;
  Wt[fidx(c, k, INDIM)] = f2b(W[idx]);
}

// gat_W [NGAT][128 k][512 (h*128+c)] -> Wt2F fragment layout (col=c, kk=h*128+k,
// K=512), head-mean 0.25 folded in.
__global__ void k_wt2(const float* __restrict__ W, unsigned short* __restrict__ Wt) {
  int idx = blockIdx.x * 256 + threadIdx.x;
  if (idx >= NGAT * HID * HEADS * HID) return;
  int l = idx / (HID * HEADS * HID);
  int rem = idx - l * HID * HEADS * HID;
  int k = rem >> 9;
  int cc = rem & 511;
  int hh = cc >> 7, c = cc & 127;
  Wt[(size_t)l * (HID * HEADS * HID) + fidx(c, hh * HID + k, HEADS * HID)] =
      f2b(W[idx] * 0.25f);
}

// x [N][256] fp32 -> xbF bf16 fragment layout (rows padded to MPAD with zeros)
__global__ void k_xfrag(const float* __restrict__ x, unsigned short* __restrict__ xbF,
                        int N) {
  int t = blockIdx.x * 256 + threadIdx.x;
  if (t >= MPAD * 32) return;
  int n = t >> 5, kc = t & 31;  // k = kc*8
  uint4 pk = make_uint4(0, 0, 0, 0);
  if (n < N) {
    const float* ap = x + (size_t)n * INDIM + kc * 8;
    float4 u = *(const float4*)ap;
    float4 v = *(const float4*)(ap + 4);
    pk.x = (unsigned)f2b(u.x) | ((unsigned)f2b(u.y) << 16);
    pk.y = (unsigned)f2b(u.z) | ((unsigned)f2b(u.w) << 16);
    pk.z = (unsigned)f2b(v.x) | ((unsigned)f2b(v.y) << 16);
    pk.w = (unsigned)f2b(v.z) | ((unsigned)f2b(v.w) << 16);
  }
  size_t addr = ((size_t)(n >> 4) * 8 + (kc >> 2)) * 512 +
                (((kc & 3) * 16 + (n & 15)) << 3);
  *(uint4*)(xbF + addr) = pk;
}

// w_s[l][h][k] = sum_c gat_W[l][k][h*128+c] * att_src[l][h][c]  (and w_d)
__global__ void k_wvec(const float* __restrict__ W, const float* __restrict__ atts,
                       const float* __restrict__ attd, float* __restrict__ w_s,
                       float* __restrict__ w_d) {
  int lane = threadIdx.x & 63;
  int idx = blockIdx.x * 4 + (threadIdx.x >> 6);
  if (idx >= NGAT * HEADS * HID) return;
  int l = idx / (HEADS * HID);
  int rem = idx - l * (HEADS * HID);
  int hh = rem >> 7, k = rem & 127;
  const float2 w2 = *(const float2*)(W + ((size_t)(l * HID + k)) * (HEADS * HID) +
                                     hh * HID + lane * 2);
  const float2 s2 = *(const float2*)(atts + (size_t)(l * HEADS + hh) * HID + lane * 2);
  const float2 d2 = *(const float2*)(attd + (size_t)(l * HEADS + hh) * HID + lane * 2);
  float ps = w2.x * s2.x + w2.y * s2.y;
  float pd = w2.x * d2.x + w2.y * d2.y;
  ps = wsum(ps);
  pd = wsum(pd);
  if (lane == 0) { w_s[idx] = ps; w_d[idx] = pd; }
}

// ---------------- projection GEMM + fused layer-0 attention logits ----------------
// h = xbF @ WtPF^T + b; a_s/a_d[n,h] = h[n]·w_s0[h]. All GEMM loads coalesced
// (fragment layout). 4 waves x 16 rows, grid = MPAD/64.
__global__ __launch_bounds__(256) void k_mm(
    const unsigned short* __restrict__ xbF, const unsigned short* __restrict__ WtPF,
    const float* __restrict__ bias, const float* __restrict__ ws0,
    const float* __restrict__ wd0, float* __restrict__ h,
    unsigned short* __restrict__ hb, float* __restrict__ a_s,
    float* __restrict__ a_d) {
  const int wid = threadIdx.x >> 6;
  const int lane = threadIdx.x & 63;
  const int l15 = lane & 15;
  const int g = lane >> 4;
  const int row0 = blockIdx.x * 64 + wid * 16;
  f32x4 acc[8] = {};
  const unsigned short* Ap = xbF + (size_t)(row0 >> 4) * 8 * 512 + lane * 8;
  const unsigned short* Bp = WtPF + lane * 8;
  for (int kb = 0; kb < 8; ++kb) {
    short8 af = *(const short8*)(Ap + kb * 512);
    short8 bfr[8];
#pragma unroll
    for (int ni = 0; ni < 8; ++ni)
      bfr[ni] = *(const short8*)(Bp + (size_t)(ni * 8 + kb) * 512);
#pragma unroll
    for (int ni = 0; ni < 8; ++ni)
      acc[ni] = __builtin_amdgcn_mfma_f32_16x16x32_bf16(af, bfr[ni], acc[ni], 0, 0, 0);
  }
#pragma unroll
  for (int r = 0; r < 4; ++r) {
    const int row = row0 + g * 4 + r;
    float* hr = h + (size_t)row * HID;
    unsigned short* hbr = hb + (size_t)row * HID;
    float yv[8];
#pragma unroll
    for (int ni = 0; ni < 8; ++ni) {
      const int c = ni * 16 + l15;
      yv[ni] = acc[ni][r] + bias[c];
      hr[c] = yv[ni];
      hbr[c] = f2b(yv[ni]);
    }
    float ps[4], pd[4];
#pragma unroll
    for (int h4 = 0; h4 < 4; ++h4) {
      float pv = 0.f, qv = 0.f;
#pragma unroll
      for (int ni = 0; ni < 8; ++ni) {
        const int c = h4 * HID + ni * 16 + l15;
        pv = fmaf(yv[ni], ws0[c], pv);
        qv = fmaf(yv[ni], wd0[c], qv);
      }
#pragma unroll
      for (int m = 1; m < 16; m <<= 1) {
        pv += __shfl_xor(pv, m, 64);
        qv += __shfl_xor(qv, m, 64);
      }
      ps[h4] = pv;
      pd[h4] = qv;
    }
    if (l15 == 0) {
      *(float4*)(a_s + (size_t)row * 4) = make_float4(ps[0], ps[1], ps[2], ps[3]);
      *(float4*)(a_d + (size_t)row * 4) = make_float4(pd[0], pd[1], pd[2], pd[3]);
    }
  }
}

// ---------------- GAT aggregation into fragment-layout aggF ----------------
// Wave per node. Lane (g,l15) owns head g, channels l15*8..+7. Alphas:
// broadcast all 4 heads from the edge's prologue lane, THEN select head g.
__global__ __launch_bounds__(256) void k_agg2(
    const int* __restrict__ rowptr, const int* __restrict__ csr,
    const unsigned short* __restrict__ hb, const float* __restrict__ a_s,
    const float* __restrict__ a_d, unsigned short* __restrict__ aggF, int N) {
  int lane = threadIdx.x & 63;
  int n = blockIdx.x * 4 + (threadIdx.x >> 6);
  if (n >= N) return;
  int beg = rowptr[n], end = rowptr[n + 1];
  int deg = end - beg;
  const float4 adv = *(const float4*)(a_d + (size_t)n * 4);
  const int g = lane >> 4;
  const int l15 = lane & 15;
  const unsigned short* hbase = hb + l15 * 8;
  float acc[8] = {};
  float f[8];
  if (deg <= 64) {
    int e = beg + lane;
    bool val = e < end;
    int s = csr[val ? e : end - 1];
    const float4 asv = *(const float4*)(a_s + (size_t)s * 4);
    float L0 = lk2(asv.x + adv.x);
    float L1 = lk2(asv.y + adv.y);
    float L2 = lk2(asv.z + adv.z);
    float L3 = lk2(asv.w + adv.w);
    float m0 = wmax(val ? L0 : -3e38f);
    float m1 = wmax(val ? L1 : -3e38f);
    float m2 = wmax(val ? L2 : -3e38f);
    float m3 = wmax(val ? L3 : -3e38f);
    float e0 = val ? exp2f(L0 - m0) : 0.f;
    float e1 = val ? exp2f(L1 - m1) : 0.f;
    float e2 = val ? exp2f(L2 - m2) : 0.f;
    float e3 = val ? exp2f(L3 - m3) : 0.f;
    float al0 = e0 / wsum(e0);
    float al1 = e1 / wsum(e1);
    float al2 = e2 / wsum(e2);
    float al3 = e3 / wsum(e3);
    int i = 0;
    for (; i + 2 <= deg; i += 2) {
      int s0 = __shfl(s, i, 64);
      int s1 = __shfl(s, i + 1, 64);
      float a00 = __shfl(al0, i, 64), a01 = __shfl(al1, i, 64);
      float a02 = __shfl(al2, i, 64), a03 = __shfl(al3, i, 64);
      float a10 = __shfl(al0, i + 1, 64), a11 = __shfl(al1, i + 1, 64);
      float a12 = __shfl(al2, i + 1, 64), a13 = __shfl(al3, i + 1, 64);
      uint4 h0 = *(const uint4*)(hbase + (size_t)s0 * HID);
      uint4 h1 = *(const uint4*)(hbase + (size_t)s1 * HID);
      float b0 = sel4(a00, a01, a02, a03, g);
      float b1 = sel4(a10, a11, a12, a13, g);
      unp8(h0, f);
#pragma unroll
      for (int j = 0; j < 8; ++j) acc[j] = fmaf(b0, f[j], acc[j]);
      unp8(h1, f);
#pragma unroll
      for (int j = 0; j < 8; ++j) acc[j] = fmaf(b1, f[j], acc[j]);
    }
    if (i < deg) {
      int s0 = __shfl(s, i, 64);
      float a00 = __shfl(al0, i, 64), a01 = __shfl(al1, i, 64);
      float a02 = __shfl(al2, i, 64), a03 = __shfl(al3, i, 64);
      uint4 h0 = *(const uint4*)(hbase + (size_t)s0 * HID);
      float b0 = sel4(a00, a01, a02, a03, g);
      unp8(h0, f);
#pragma unroll
      for (int j = 0; j < 8; ++j) acc[j] = fmaf(b0, f[j], acc[j]);
    }
  } else {
    float m0 = -3e38f, m1 = -3e38f, m2 = -3e38f, m3 = -3e38f;
    for (int e = beg + lane; e < end; e += 64) {
      int s = csr[e];
      const float4 asv = *(const float4*)(a_s + (size_t)s * 4);
      m0 = fmaxf(m0, lk2(asv.x + adv.x));
      m1 = fmaxf(m1, lk2(asv.y + adv.y));
      m2 = fmaxf(m2, lk2(asv.z + adv.z));
      m3 = fmaxf(m3, lk2(asv.w + adv.w));
    }
    m0 = wmax(m0); m1 = wmax(m1); m2 = wmax(m2); m3 = wmax(m3);
    float d0 = 0.f, d1 = 0.f, d2 = 0.f, d3 = 0.f;
    for (int e = beg + lane; e < end; e += 64) {
      int s = csr[e];
      const float4 asv = *(const float4*)(a_s + (size_t)s * 4);
      d0 += exp2f(lk2(asv.x + adv.x) - m0);
      d1 += exp2f(lk2(asv.y + adv.y) - m1);
      d2 += exp2f(lk2(asv.z + adv.z) - m2);
      d3 += exp2f(lk2(asv.w + adv.w) - m3);
    }
    float r0 = 1.f / wsum(d0);
    float r1 = 1.f / wsum(d1);
    float r2 = 1.f / wsum(d2);
    float r3 = 1.f / wsum(d3);
    for (int sb = beg; sb < end; sb += 64) {
      int e = sb + lane;
      bool val = e < end;
      int s = csr[val ? e : end - 1];
      const float4 asv = *(const float4*)(a_s + (size_t)s * 4);
      float q0 = val ? exp2f(lk2(asv.x + adv.x) - m0) * r0 : 0.f;
      float q1 = val ? exp2f(lk2(asv.y + adv.y) - m1) * r1 : 0.f;
      float q2 = val ? exp2f(lk2(asv.z + adv.z) - m2) * r2 : 0.f;
      float q3 = val ? exp2f(lk2(asv.w + adv.w) - m3) * r3 : 0.f;
      int cnt = min(64, end - sb);
      for (int i = 0; i < cnt; ++i) {
        int si = __shfl(s, i, 64);
        float c0 = __shfl(q0, i, 64), c1 = __shfl(q1, i, 64);
        float c2 = __shfl(q2, i, 64), c3 = __shfl(q3, i, 64);
        uint4 hv = *(const uint4*)(hbase + (size_t)si * HID);
        float bi = sel4(c0, c1, c2, c3, g);
        unp8(hv, f);
#pragma unroll
        for (int j = 0; j < 8; ++j) acc[j] = fmaf(bi, f[j], acc[j]);
      }
    }
  }
  uint4 pk;
  pk.x = (unsigned)f2b(acc[0]) | ((unsigned)f2b(acc[1]) << 16);
  pk.y = (unsigned)f2b(acc[2]) | ((unsigned)f2b(acc[3]) << 16);
  pk.z = (unsigned)f2b(acc[4]) | ((unsigned)f2b(acc[5]) << 16);
  pk.w = (unsigned)f2b(acc[6]) | ((unsigned)f2b(acc[7]) << 16);
  // fragment-layout store: row n, k-dim kk0 = g*128 + l15*8
  size_t addr = ((size_t)(n >> 4) * 16 + (g * 4 + (l15 >> 2))) * 512 +
                (((l15 & 3) * 16 + (n & 15)) << 3);
  *(uint4*)(aggF + addr) = pk;
}

// ---------------- post-agg GEMM + bias+LN+ReLU+residual + fused next-layer att
// (ATT=1) or fused GCN xw (ATT=2). C = aggF @ Wt2F^T. 4 waves x 16 rows.
template <int ATT>
__global__ __launch_bounds__(256) void k_mm2(
    const unsigned short* __restrict__ aggF, const unsigned short* __restrict__ Bt,
    const float* __restrict__ bias, const float* __restrict__ gamma,
    const float* __restrict__ beta, const float* __restrict__ wsn,
    const float* __restrict__ wdn, float* __restrict__ h,
    unsigned short* __restrict__ hb, float* __restrict__ a_s,
    float* __restrict__ a_d, float* __restrict__ xw) {
  const int wid = threadIdx.x >> 6;
  const int lane = threadIdx.x & 63;
  const int l15 = lane & 15;
  const int g = lane >> 4;
  const int row0 = blockIdx.x * 64 + wid * 16;
  f32x4 acc[8] = {};
  const unsigned short* Ap = aggF + (size_t)(row0 >> 4) * 16 * 512 + lane * 8;
  const unsigned short* Bp = Bt + lane * 8;
  for (int kb = 0; kb < 16; ++kb) {
    short8 a0 = *(const short8*)(Ap + kb * 512);
    short8 bfr[8];
#pragma unroll
    for (int ni = 0; ni < 8; ++ni)
      bfr[ni] = *(const short8*)(Bp + (size_t)(ni * 16 + kb) * 512);
#pragma unroll
    for (int ni = 0; ni < 8; ++ni)
      acc[ni] = __builtin_amdgcn_mfma_f32_16x16x32_bf16(a0, bfr[ni], acc[ni], 0, 0, 0);
  }
  float gm[8], bt8[8];
#pragma unroll
  for (int ni = 0; ni < 8; ++ni) {
    int c = ni * 16 + l15;
    gm[ni] = gamma[c];
    bt8[ni] = beta[c];
    float bs = bias[c];
#pragma unroll
    for (int r = 0; r < 4; ++r) acc[ni][r] += bs;
  }
#pragma unroll
  for (int r = 0; r < 4; ++r) {
    float s = 0.f;
#pragma unroll
    for (int ni = 0; ni < 8; ++ni) s += acc[ni][r];
#pragma unroll
    for (int m = 1; m < 16; m <<= 1) s += __shfl_xor(s, m, 64);
    float mu = s * (1.f / 128.f);
    float q = 0.f;
#pragma unroll
    for (int ni = 0; ni < 8; ++ni) {
      float dd = acc[ni][r] - mu;
      q += dd * dd;
    }
#pragma unroll
    for (int m = 1; m < 16; m <<= 1) q += __shfl_xor(q, m, 64);
    float rstd = rsqrtf(q * (1.f / 128.f) + LN_EPS);
    const int row = row0 + g * 4 + r;
    float* hr = h + (size_t)row * HID;
    unsigned short* hbr = hb + (size_t)row * HID;
    float yv[8];
#pragma unroll
    for (int ni = 0; ni < 8; ++ni) {
      int c = ni * 16 + l15;
      float y = (acc[ni][r] - mu) * rstd * gm[ni] + bt8[ni];
      y = fmaxf(y, 0.f) + hr[c];
      hr[c] = y;
      hbr[c] = f2b(y);
      yv[ni] = y;
    }
    if (ATT == 1) {
      float ps[4], pd[4];
#pragma unroll
      for (int h4 = 0; h4 < 4; ++h4) {
        float pv = 0.f, qv = 0.f;
#pragma unroll
        for (int ni = 0; ni < 8; ++ni) {
          const int c = h4 * HID + ni * 16 + l15;
          pv = fmaf(yv[ni], wsn[c], pv);
          qv = fmaf(yv[ni], wdn[c], qv);
        }
#pragma unroll
        for (int m = 1; m < 16; m <<= 1) {
          pv += __shfl_xor(pv, m, 64);
          qv += __shfl_xor(qv, m, 64);
        }
        ps[h4] = pv;
        pd[h4] = qv;
      }
      if (l15 == 0) {
        *(float4*)(a_s + (size_t)row * 4) = make_float4(ps[0], ps[1], ps[2], ps[3]);
        *(float4*)(a_d + (size_t)row * 4) = make_float4(pd[0], pd[1], pd[2], pd[3]);
      }
    } else {
      float pv = 0.f;
#pragma unroll
      for (int ni = 0; ni < 8; ++ni) pv = fmaf(yv[ni], wsn[ni * 16 + l15], pv);
#pragma unroll
      for (int m = 1; m < 16; m <<= 1) pv += __shfl_xor(pv, m, 64);
      if (l15 == 0) xw[row] = pv;
    }
  }
}

// ---------------- GCN head ----------------
__global__ __launch_bounds__(256) void k_gcn(const int* __restrict__ rowptr,
                                             const int* __restrict__ csr,
                                             const float* __restrict__ xw,
                                             const float* __restrict__ dinv,
                                             const float* __restrict__ gcn_b,
                                             float* __restrict__ out, int N) {
  int n = blockIdx.x * blockDim.x + threadIdx.x;
  if (n >= N) return;
  float acc = 0.f;
  int beg = rowptr[n], end = rowptr[n + 1];
  for (int e = beg; e < end; ++e) {
    int s = csr[e];
    acc += xw[s] * dinv[s];
  }
  float z = acc * dinv[n] + gcn_b[0];
  out[n] = 1.f / (1.f + expf(-z));
}

extern "C" void kernel_launch(void* const* d_in, const int* in_sizes, int n_in,
                              void* d_out, int out_size, void* d_ws, size_t ws_size,
                              hipStream_t stream) {
  const float* x = (const float*)d_in[0];
  const int* ei = (const int*)d_in[1];
  const float* proj_W = (const float*)d_in[2];
  const float* proj_b = (const float*)d_in[3];
  const float* gat_W = (const float*)d_in[4];
  const float* gat_as = (const float*)d_in[5];
  const float* gat_ad = (const float*)d_in[6];
  const float* gat_bias = (const float*)d_in[7];
  const float* ln_g = (const float*)d_in[8];
  const float* ln_b = (const float*)d_in[9];
  const float* gcn_W = (const float*)d_in[10];
  const float* gcn_b = (const float*)d_in[11];
  float* out = (float*)d_out;

  const int N = in_sizes[0] / INDIM;  // 40000
  const int E = in_sizes[1] / 2;      // 320000
  const int TOT = E + N;

  size_t off = 0;
  auto alloc = [&](size_t bytes) {
    void* p = (char*)d_ws + off;
    off += (bytes + 255) & ~(size_t)255;
    return p;
  };
  float* h = (float*)alloc((size_t)MPAD * HID * 4);
  unsigned short* hb = (unsigned short*)alloc((size_t)MPAD * HID * 2);
  unsigned short* aggF = (unsigned short*)alloc((size_t)MPAD * HEADS * HID * 2);
  unsigned short* xbF = (unsigned short*)alloc((size_t)MPAD * INDIM * 2);
  unsigned short* WtPF = (unsigned short*)alloc((size_t)HID * INDIM * 2);
  unsigned short* Wt2F = (unsigned short*)alloc((size_t)NGAT * HID * HEADS * HID * 2);
  float* w_s = (float*)alloc((size_t)NGAT * HEADS * HID * 4);
  float* w_d = (float*)alloc((size_t)NGAT * HEADS * HID * 4);
  float* a_s = (float*)alloc((size_t)MPAD * HEADS * 4);
  float* a_d = (float*)alloc((size_t)MPAD * HEADS * 4);
  int* deg = (int*)alloc((size_t)N * 4);
  int* rowptr = (int*)alloc((size_t)(N + 1) * 4);
  int* cursor = (int*)alloc((size_t)N * 4);
  int* csr = (int*)alloc((size_t)TOT * 4);
  int* bsums = (int*)alloc(1024);
  float* dinv = (float*)alloc((size_t)N * 4);
  float* xw = (float*)alloc((size_t)MPAD * 4);
  (void)ws_size;

  const int NBLK = (N + 255) / 256;
  const int EBLK = (TOT + 255) / 256;
  const int WBLK = (N + 3) / 4;

  // CSR build
  hipMemsetAsync(deg, 0, (size_t)N * 4, stream);
  k_deg<<<EBLK, 256, 0, stream>>>(ei, E, N, deg);
  k_scan1<<<NBLK, 256, 0, stream>>>(deg, N, bsums);
  k_scan2<<<1, 1, 0, stream>>>(bsums, NBLK, rowptr, N);
  k_scan3<<<NBLK, 256, 0, stream>>>(deg, N, bsums, rowptr, cursor, dinv);
  k_fill<<<EBLK, 256, 0, stream>>>(ei, E, N, cursor, csr);

  // weight/input prep (fragment layouts)
  k_wtp<<<(INDIM * HID + 255) / 256, 256, 0, stream>>>(proj_W, WtPF);
  k_wt2<<<(NGAT * HID * HEADS * HID + 255) / 256, 256, 0, stream>>>(gat_W, Wt2F);
  k_wvec<<<(NGAT * HEADS * HID + 3) / 4, 256, 0, stream>>>(gat_W, gat_as, gat_ad, w_s, w_d);
  k_xfrag<<<(MPAD * 32 + 255) / 256, 256, 0, stream>>>(x, xbF, N);

  // zero aggF pad rows (N%16==0 -> pad region is a contiguous tail)
  hipMemsetAsync(aggF + (size_t)N * HEADS * HID, 0,
                 (size_t)(MPAD - N) * HEADS * HID * 2, stream);

  // projection + layer-0 attention logits
  k_mm<<<MPAD / 64, 256, 0, stream>>>(xbF, WtPF, proj_b, w_s, w_d, h, hb, a_s, a_d);

  for (int i = 0; i < NGAT; ++i) {
    k_agg2<<<WBLK, 256, 0, stream>>>(rowptr, csr, hb, a_s, a_d, aggF, N);
    if (i < NGAT - 1) {
      k_mm2<1><<<MPAD / 64, 256, 0, stream>>>(
          aggF, Wt2F + (size_t)i * HID * HEADS * HID, gat_bias + (size_t)i * HID,
          ln_g + (size_t)i * HID, ln_b + (size_t)i * HID,
          w_s + (size_t)(i + 1) * HEADS * HID, w_d + (size_t)(i + 1) * HEADS * HID,
          h, hb, a_s, a_d, nullptr);
    } else {
      k_mm2<2><<<MPAD / 64, 256, 0, stream>>>(
          aggF, Wt2F + (size_t)i * HID * HEADS * HID, gat_bias + (size_t)i * HID,
          ln_g + (size_t)i * HID, ln_b + (size_t)i * HID, gcn_W, nullptr,
          h, hb, nullptr, nullptr, xw);
    }
  }

  // GCN head
  k_gcn<<<NBLK, 256, 0, stream>>>(rowptr, csr, xw, dinv, gcn_b, out, N);
}

// Round 8
// 293.943 us; speedup vs baseline: 3.5433x; 1.1541x over previous
//
#include <hip/hip_runtime.h>
#include <math.h>

#define INDIM 256
#define HID 128
#define HEADS 4
#define NGAT 3
#define LN_EPS 1e-5f
#define SLOPE 0.2f
#define MPAD 40064  // 313 * 128; N=40000 is divisible by 16
#define LOG2E 1.4426950408889634f

typedef __attribute__((ext_vector_type(8))) short short8;
typedef __attribute__((ext_vector_type(4))) float f32x4;

__device__ inline float wsum(float v) {
#pragma unroll
  for (int m = 1; m < 64; m <<= 1) v += __shfl_xor(v, m, 64);
  return v;
}
__device__ inline float wmax(float v) {
#pragma unroll
  for (int m = 1; m < 64; m <<= 1) v = fmaxf(v, __shfl_xor(v, m, 64));
  return v;
}
// leaky_relu then scale to exp2 domain
__device__ inline float lk2(float v) { return fmaxf(v, SLOPE * v) * LOG2E; }
// static-select (broadcast BEFORE select — round-5 lesson)
__device__ inline float sel4(float a0, float a1, float a2, float a3, int i) {
  float lo = (i & 1) ? a1 : a0;
  float hi = (i & 1) ? a3 : a2;
  return (i & 2) ? hi : lo;
}

__device__ inline unsigned short f2b(float f) {
  unsigned u = __float_as_uint(f);
  unsigned r = (u + 0x7FFFu + ((u >> 16) & 1u)) >> 16;
  return (unsigned short)r;
}
__device__ inline void unp8(const uint4 v, float f[8]) {
  f[0] = __uint_as_float(v.x << 16);
  f[1] = __uint_as_float(v.x & 0xFFFF0000u);
  f[2] = __uint_as_float(v.y << 16);
  f[3] = __uint_as_float(v.y & 0xFFFF0000u);
  f[4] = __uint_as_float(v.z << 16);
  f[5] = __uint_as_float(v.z & 0xFFFF0000u);
  f[6] = __uint_as_float(v.w << 16);
  f[7] = __uint_as_float(v.w & 0xFFFF0000u);
}

// MFMA fragment layout index: element (row,k) of a [rows][K] bf16 matrix.
__device__ __host__ inline size_t fidx(int row, int k, int K) {
  return ((size_t)(row >> 4) * (K >> 5) + (k >> 5)) * 512 +
         ((((k >> 3) & 3) * 16 + (row & 15)) << 3) + (k & 7);
}

// ---------------- CSR construction ----------------
__global__ void k_deg(const int* __restrict__ ei, int E, int N, int* __restrict__ deg) {
  int e = blockIdx.x * blockDim.x + threadIdx.x;
  if (e >= E + N) return;
  int dst = (e < E) ? ei[E + e] : (e - E);
  atomicAdd(&deg[dst], 1);
}

__global__ void k_scan1(const int* __restrict__ deg, int N, int* __restrict__ bsums) {
  __shared__ int s[256];
  int gid = blockIdx.x * 256 + threadIdx.x;
  s[threadIdx.x] = (gid < N) ? deg[gid] : 0;
  __syncthreads();
  for (int off = 128; off > 0; off >>= 1) {
    if (threadIdx.x < off) s[threadIdx.x] += s[threadIdx.x + off];
    __syncthreads();
  }
  if (threadIdx.x == 0) bsums[blockIdx.x] = s[0];
}

// one-block parallel scan over block sums (nblk <= 256)
__global__ void k_scan2(int* __restrict__ bsums, int nblk, int* __restrict__ rowptr, int N) {
  __shared__ int s[256];
  int t = threadIdx.x;
  int v = (t < nblk) ? bsums[t] : 0;
  s[t] = v;
  __syncthreads();
  for (int off = 1; off < 256; off <<= 1) {
    int u = (t >= off) ? s[t - off] : 0;
    __syncthreads();
    s[t] += u;
    __syncthreads();
  }
  if (t < nblk) bsums[t] = s[t] - v;  // exclusive
  if (t == nblk - 1) rowptr[N] = s[t];
}

__global__ void k_scan3(const int* __restrict__ deg, int N, const int* __restrict__ bsums,
                        int* __restrict__ rowptr, int* __restrict__ cursor,
                        float* __restrict__ dinv) {
  __shared__ int s[256];
  int gid = blockIdx.x * 256 + threadIdx.x;
  int v = (gid < N) ? deg[gid] : 0;
  s[threadIdx.x] = v;
  __syncthreads();
  for (int off = 1; off < 256; off <<= 1) {
    int t = (threadIdx.x >= off) ? s[threadIdx.x - off] : 0;
    __syncthreads();
    s[threadIdx.x] += t;
    __syncthreads();
  }
  if (gid < N) {
    int ex = bsums[blockIdx.x] + s[threadIdx.x] - v;
    rowptr[gid] = ex;
    cursor[gid] = ex;
    dinv[gid] = rsqrtf((float)v);
  }
}

__global__ void k_fill(const int* __restrict__ ei, int E, int N,
                       int* __restrict__ cursor, int* __restrict__ csr) {
  int e = blockIdx.x * blockDim.x + threadIdx.x;
  if (e >= E + N) return;
  int src, dst;
  if (e < E) { src = ei[e]; dst = ei[E + e]; } else { src = dst = e - E; }
  int pos = atomicAdd(&cursor[dst], 1);
  csr[pos] = src;
}

// ---------------- weight/input prep (fragment layouts) ----------------
__global__ void k_wtp(const float* __restrict__ W, unsigned short* __restrict__ Wt) {
  int idx = blockIdx.x * 256 + threadIdx.x;
  if (idx >= INDIM * HID) return;
  int k = idx >> 7, c = idx & 127;
  Wt[fidx(c, k, INDIM)] = f2b(W[idx]);
}

__global__ void k_wt2(const float* __restrict__ W, unsigned short* __restrict__ Wt) {
  int idx = blockIdx.x * 256 + threadIdx.x;
  if (idx >= NGAT * HID * HEADS * HID) return;
  int l = idx / (HID * HEADS * HID);
  int rem = idx - l * HID * HEADS * HID;
  int k = rem >> 9;
  int cc = rem & 511;
  int hh = cc >> 7, c = cc & 127;
  Wt[(size_t)l * (HID * HEADS * HID) + fidx(c, hh * HID + k, HEADS * HID)] =
      f2b(W[idx] * 0.25f);
}

__global__ void k_xfrag(const float* __restrict__ x, unsigned short* __restrict__ xbF,
                        int N) {
  int t = blockIdx.x * 256 + threadIdx.x;
  if (t >= MPAD * 32) return;
  int n = t >> 5, kc = t & 31;  // k = kc*8
  uint4 pk = make_uint4(0, 0, 0, 0);
  if (n < N) {
    const float* ap = x + (size_t)n * INDIM + kc * 8;
    float4 u = *(const float4*)ap;
    float4 v = *(const float4*)(ap + 4);
    pk.x = (unsigned)f2b(u.x) | ((unsigned)f2b(u.y) << 16);
    pk.y = (unsigned)f2b(u.z) | ((unsigned)f2b(u.w) << 16);
    pk.z = (unsigned)f2b(v.x) | ((unsigned)f2b(v.y) << 16);
    pk.w = (unsigned)f2b(v.z) | ((unsigned)f2b(v.w) << 16);
  }
  size_t addr = ((size_t)(n >> 4) * 8 + (kc >> 2)) * 512 +
                (((kc & 3) * 16 + (n & 15)) << 3);
  *(uint4*)(xbF + addr) = pk;
}

// w_s[l][h][k] = sum_c gat_W[l][k][h*128+c] * att_src[l][h][c]  (and w_d)
__global__ void k_wvec(const float* __restrict__ W, const float* __restrict__ atts,
                       const float* __restrict__ attd, float* __restrict__ w_s,
                       float* __restrict__ w_d) {
  int lane = threadIdx.x & 63;
  int idx = blockIdx.x * 4 + (threadIdx.x >> 6);
  if (idx >= NGAT * HEADS * HID) return;
  int l = idx / (HEADS * HID);
  int rem = idx - l * (HEADS * HID);
  int hh = rem >> 7, k = rem & 127;
  const float2 w2 = *(const float2*)(W + ((size_t)(l * HID + k)) * (HEADS * HID) +
                                     hh * HID + lane * 2);
  const float2 s2 = *(const float2*)(atts + (size_t)(l * HEADS + hh) * HID + lane * 2);
  const float2 d2 = *(const float2*)(attd + (size_t)(l * HEADS + hh) * HID + lane * 2);
  float ps = w2.x * s2.x + w2.y * s2.y;
  float pd = w2.x * d2.x + w2.y * d2.y;
  ps = wsum(ps);
  pd = wsum(pd);
  if (lane == 0) { w_s[idx] = ps; w_d[idx] = pd; }
}

// ---------------- projection GEMM + fused layer-0 attention logits ----------------
__global__ __launch_bounds__(256) void k_mm(
    const unsigned short* __restrict__ xbF, const unsigned short* __restrict__ WtPF,
    const float* __restrict__ bias, const float* __restrict__ ws0,
    const float* __restrict__ wd0, float* __restrict__ h,
    unsigned short* __restrict__ hb, float* __restrict__ a_s,
    float* __restrict__ a_d) {
  const int wid = threadIdx.x >> 6;
  const int lane = threadIdx.x & 63;
  const int l15 = lane & 15;
  const int g = lane >> 4;
  const int row0 = blockIdx.x * 64 + wid * 16;
  f32x4 acc[8] = {};
  const unsigned short* Ap = xbF + (size_t)(row0 >> 4) * 8 * 512 + lane * 8;
  const unsigned short* Bp = WtPF + lane * 8;
  for (int kb = 0; kb < 8; ++kb) {
    short8 af = *(const short8*)(Ap + kb * 512);
    short8 bfr[8];
#pragma unroll
    for (int ni = 0; ni < 8; ++ni)
      bfr[ni] = *(const short8*)(Bp + (size_t)(ni * 8 + kb) * 512);
#pragma unroll
    for (int ni = 0; ni < 8; ++ni)
      acc[ni] = __builtin_amdgcn_mfma_f32_16x16x32_bf16(af, bfr[ni], acc[ni], 0, 0, 0);
  }
#pragma unroll
  for (int r = 0; r < 4; ++r) {
    const int row = row0 + g * 4 + r;
    float* hr = h + (size_t)row * HID;
    unsigned short* hbr = hb + (size_t)row * HID;
    float yv[8];
#pragma unroll
    for (int ni = 0; ni < 8; ++ni) {
      const int c = ni * 16 + l15;
      yv[ni] = acc[ni][r] + bias[c];
      hr[c] = yv[ni];
      hbr[c] = f2b(yv[ni]);
    }
    float ps[4], pd[4];
#pragma unroll
    for (int h4 = 0; h4 < 4; ++h4) {
      float pv = 0.f, qv = 0.f;
#pragma unroll
      for (int ni = 0; ni < 8; ++ni) {
        const int c = h4 * HID + ni * 16 + l15;
        pv = fmaf(yv[ni], ws0[c], pv);
        qv = fmaf(yv[ni], wd0[c], qv);
      }
#pragma unroll
      for (int m = 1; m < 16; m <<= 1) {
        pv += __shfl_xor(pv, m, 64);
        qv += __shfl_xor(qv, m, 64);
      }
      ps[h4] = pv;
      pd[h4] = qv;
    }
    if (l15 == 0) {
      *(float4*)(a_s + (size_t)row * 4) = make_float4(ps[0], ps[1], ps[2], ps[3]);
      *(float4*)(a_d + (size_t)row * 4) = make_float4(pd[0], pd[1], pd[2], pd[3]);
    }
  }
}

// ---------------- GAT aggregation into fragment-layout aggF ----------------
// Wave per node. Prologue parks each edge's src + 4 alphas in LDS; gather loop
// reads them via 2 ds_read_b128 per 4 edges (no shfl/sel in the loop) and keeps
// 4 row loads in flight. Lane (g,l15) owns head g, channels l15*8..+7.
__global__ __launch_bounds__(256) void k_agg2(
    const int* __restrict__ rowptr, const int* __restrict__ csr,
    const unsigned short* __restrict__ hb, const float* __restrict__ a_s,
    const float* __restrict__ a_d, unsigned short* __restrict__ aggF, int N) {
  __shared__ int s_lds[4][64];
  __shared__ float al_lds[4][4][68];  // stride 68: head-groups hit distinct banks
  int lane = threadIdx.x & 63;
  int wid = threadIdx.x >> 6;
  int n = blockIdx.x * 4 + wid;
  if (n >= N) return;
  int beg = rowptr[n], end = rowptr[n + 1];
  int deg = end - beg;
  const float4 adv = *(const float4*)(a_d + (size_t)n * 4);
  const int g = lane >> 4;
  const int l15 = lane & 15;
  const unsigned short* hbase = hb + l15 * 8;
  float acc[8] = {};
  float f[8];
  if (deg <= 64) {
    // prologue: lane i <-> edge beg+i
    int e = beg + lane;
    bool val = e < end;
    int s = csr[val ? e : end - 1];
    const float4 asv = *(const float4*)(a_s + (size_t)s * 4);
    float L0 = lk2(asv.x + adv.x);
    float L1 = lk2(asv.y + adv.y);
    float L2 = lk2(asv.z + adv.z);
    float L3 = lk2(asv.w + adv.w);
    float m0 = wmax(val ? L0 : -3e38f);
    float m1 = wmax(val ? L1 : -3e38f);
    float m2 = wmax(val ? L2 : -3e38f);
    float m3 = wmax(val ? L3 : -3e38f);
    float e0 = val ? exp2f(L0 - m0) : 0.f;
    float e1 = val ? exp2f(L1 - m1) : 0.f;
    float e2 = val ? exp2f(L2 - m2) : 0.f;
    float e3 = val ? exp2f(L3 - m3) : 0.f;
    // invalid lanes: e? = 0 -> alpha = 0 (loop tail is then a free no-op fma)
    s_lds[wid][lane] = s;
    al_lds[wid][0][lane] = e0 / wsum(e0);
    al_lds[wid][1][lane] = e1 / wsum(e1);
    al_lds[wid][2][lane] = e2 / wsum(e2);
    al_lds[wid][3][lane] = e3 / wsum(e3);
    asm volatile("s_waitcnt lgkmcnt(0)" ::: "memory");
    const int* sw = s_lds[wid];
    const float* aw = al_lds[wid][g];
    int nIter = (deg + 3) >> 2;
    for (int it = 0; it < nIter; ++it) {
      int4 s4 = *(const int4*)(sw + it * 4);       // uniform -> broadcast
      float4 a4 = *(const float4*)(aw + it * 4);   // 4 addrs, conflict-free
      uint4 r0 = *(const uint4*)(hbase + (size_t)s4.x * HID);
      uint4 r1 = *(const uint4*)(hbase + (size_t)s4.y * HID);
      uint4 r2 = *(const uint4*)(hbase + (size_t)s4.z * HID);
      uint4 r3 = *(const uint4*)(hbase + (size_t)s4.w * HID);
      unp8(r0, f);
#pragma unroll
      for (int j = 0; j < 8; ++j) acc[j] = fmaf(a4.x, f[j], acc[j]);
      unp8(r1, f);
#pragma unroll
      for (int j = 0; j < 8; ++j) acc[j] = fmaf(a4.y, f[j], acc[j]);
      unp8(r2, f);
#pragma unroll
      for (int j = 0; j < 8; ++j) acc[j] = fmaf(a4.z, f[j], acc[j]);
      unp8(r3, f);
#pragma unroll
      for (int j = 0; j < 8; ++j) acc[j] = fmaf(a4.w, f[j], acc[j]);
    }
  } else {
    // rare fallback (deg > 64): strip-wise with shfl broadcast
    float m0 = -3e38f, m1 = -3e38f, m2 = -3e38f, m3 = -3e38f;
    for (int e = beg + lane; e < end; e += 64) {
      int s = csr[e];
      const float4 asv = *(const float4*)(a_s + (size_t)s * 4);
      m0 = fmaxf(m0, lk2(asv.x + adv.x));
      m1 = fmaxf(m1, lk2(asv.y + adv.y));
      m2 = fmaxf(m2, lk2(asv.z + adv.z));
      m3 = fmaxf(m3, lk2(asv.w + adv.w));
    }
    m0 = wmax(m0); m1 = wmax(m1); m2 = wmax(m2); m3 = wmax(m3);
    float d0 = 0.f, d1 = 0.f, d2 = 0.f, d3 = 0.f;
    for (int e = beg + lane; e < end; e += 64) {
      int s = csr[e];
      const float4 asv = *(const float4*)(a_s + (size_t)s * 4);
      d0 += exp2f(lk2(asv.x + adv.x) - m0);
      d1 += exp2f(lk2(asv.y + adv.y) - m1);
      d2 += exp2f(lk2(asv.z + adv.z) - m2);
      d3 += exp2f(lk2(asv.w + adv.w) - m3);
    }
    float r0 = 1.f / wsum(d0);
    float r1 = 1.f / wsum(d1);
    float r2 = 1.f / wsum(d2);
    float r3 = 1.f / wsum(d3);
    for (int sb = beg; sb < end; sb += 64) {
      int e = sb + lane;
      bool val = e < end;
      int s = csr[val ? e : end - 1];
      const float4 asv = *(const float4*)(a_s + (size_t)s * 4);
      float q0 = val ? exp2f(lk2(asv.x + adv.x) - m0) * r0 : 0.f;
      float q1 = val ? exp2f(lk2(asv.y + adv.y) - m1) * r1 : 0.f;
      float q2 = val ? exp2f(lk2(asv.z + adv.z) - m2) * r2 : 0.f;
      float q3 = val ? exp2f(lk2(asv.w + adv.w) - m3) * r3 : 0.f;
      int cnt = min(64, end - sb);
      for (int i = 0; i < cnt; ++i) {
        int si = __shfl(s, i, 64);
        float c0 = __shfl(q0, i, 64), c1 = __shfl(q1, i, 64);
        float c2 = __shfl(q2, i, 64), c3 = __shfl(q3, i, 64);
        uint4 hv = *(const uint4*)(hbase + (size_t)si * HID);
        float bi = sel4(c0, c1, c2, c3, g);
        unp8(hv, f);
#pragma unroll
        for (int j = 0; j < 8; ++j) acc[j] = fmaf(bi, f[j], acc[j]);
      }
    }
  }
  uint4 pk;
  pk.x = (unsigned)f2b(acc[0]) | ((unsigned)f2b(acc[1]) << 16);
  pk.y = (unsigned)f2b(acc[2]) | ((unsigned)f2b(acc[3]) << 16);
  pk.z = (unsigned)f2b(acc[4]) | ((unsigned)f2b(acc[5]) << 16);
  pk.w = (unsigned)f2b(acc[6]) | ((unsigned)f2b(acc[7]) << 16);
  // fragment-layout store: row n, k-dim kk0 = g*128 + l15*8
  size_t addr = ((size_t)(n >> 4) * 16 + (g * 4 + (l15 >> 2))) * 512 +
                (((l15 & 3) * 16 + (n & 15)) << 3);
  *(uint4*)(aggF + addr) = pk;
}

// ---------------- post-agg GEMM + bias+LN+ReLU+residual + fused next-layer att
// (ATT=1) or fused GCN xw (ATT=2). C = aggF @ Wt2F^T. 4 waves x 16 rows.
template <int ATT>
__global__ __launch_bounds__(256) void k_mm2(
    const unsigned short* __restrict__ aggF, const unsigned short* __restrict__ Bt,
    const float* __restrict__ bias, const float* __restrict__ gamma,
    const float* __restrict__ beta, const float* __restrict__ wsn,
    const float* __restrict__ wdn, float* __restrict__ h,
    unsigned short* __restrict__ hb, float* __restrict__ a_s,
    float* __restrict__ a_d, float* __restrict__ xw) {
  const int wid = threadIdx.x >> 6;
  const int lane = threadIdx.x & 63;
  const int l15 = lane & 15;
  const int g = lane >> 4;
  const int row0 = blockIdx.x * 64 + wid * 16;
  f32x4 acc[8] = {};
  const unsigned short* Ap = aggF + (size_t)(row0 >> 4) * 16 * 512 + lane * 8;
  const unsigned short* Bp = Bt + lane * 8;
  for (int kb = 0; kb < 16; ++kb) {
    short8 a0 = *(const short8*)(Ap + kb * 512);
    short8 bfr[8];
#pragma unroll
    for (int ni = 0; ni < 8; ++ni)
      bfr[ni] = *(const short8*)(Bp + (size_t)(ni * 16 + kb) * 512);
#pragma unroll
    for (int ni = 0; ni < 8; ++ni)
      acc[ni] = __builtin_amdgcn_mfma_f32_16x16x32_bf16(a0, bfr[ni], acc[ni], 0, 0, 0);
  }
  float gm[8], bt8[8];
#pragma unroll
  for (int ni = 0; ni < 8; ++ni) {
    int c = ni * 16 + l15;
    gm[ni] = gamma[c];
    bt8[ni] = beta[c];
    float bs = bias[c];
#pragma unroll
    for (int r = 0; r < 4; ++r) acc[ni][r] += bs;
  }
#pragma unroll
  for (int r = 0; r < 4; ++r) {
    float s = 0.f;
#pragma unroll
    for (int ni = 0; ni < 8; ++ni) s += acc[ni][r];
#pragma unroll
    for (int m = 1; m < 16; m <<= 1) s += __shfl_xor(s, m, 64);
    float mu = s * (1.f / 128.f);
    float q = 0.f;
#pragma unroll
    for (int ni = 0; ni < 8; ++ni) {
      float dd = acc[ni][r] - mu;
      q += dd * dd;
    }
#pragma unroll
    for (int m = 1; m < 16; m <<= 1) q += __shfl_xor(q, m, 64);
    float rstd = rsqrtf(q * (1.f / 128.f) + LN_EPS);
    const int row = row0 + g * 4 + r;
    float* hr = h + (size_t)row * HID;
    unsigned short* hbr = hb + (size_t)row * HID;
    float yv[8];
#pragma unroll
    for (int ni = 0; ni < 8; ++ni) {
      int c = ni * 16 + l15;
      float y = (acc[ni][r] - mu) * rstd * gm[ni] + bt8[ni];
      y = fmaxf(y, 0.f) + hr[c];
      hr[c] = y;
      hbr[c] = f2b(y);
      yv[ni] = y;
    }
    if (ATT == 1) {
      float ps[4], pd[4];
#pragma unroll
      for (int h4 = 0; h4 < 4; ++h4) {
        float pv = 0.f, qv = 0.f;
#pragma unroll
        for (int ni = 0; ni < 8; ++ni) {
          const int c = h4 * HID + ni * 16 + l15;
          pv = fmaf(yv[ni], wsn[c], pv);
          qv = fmaf(yv[ni], wdn[c], qv);
        }
#pragma unroll
        for (int m = 1; m < 16; m <<= 1) {
          pv += __shfl_xor(pv, m, 64);
          qv += __shfl_xor(qv, m, 64);
        }
        ps[h4] = pv;
        pd[h4] = qv;
      }
      if (l15 == 0) {
        *(float4*)(a_s + (size_t)row * 4) = make_float4(ps[0], ps[1], ps[2], ps[3]);
        *(float4*)(a_d + (size_t)row * 4) = make_float4(pd[0], pd[1], pd[2], pd[3]);
      }
    } else {
      float pv = 0.f;
#pragma unroll
      for (int ni = 0; ni < 8; ++ni) pv = fmaf(yv[ni], wsn[ni * 16 + l15], pv);
#pragma unroll
      for (int m = 1; m < 16; m <<= 1) pv += __shfl_xor(pv, m, 64);
      if (l15 == 0) xw[row] = pv;
    }
  }
}

// ---------------- GCN head ----------------
__global__ __launch_bounds__(256) void k_gcn(const int* __restrict__ rowptr,
                                             const int* __restrict__ csr,
                                             const float* __restrict__ xw,
                                             const float* __restrict__ dinv,
                                             const float* __restrict__ gcn_b,
                                             float* __restrict__ out, int N) {
  int n = blockIdx.x * blockDim.x + threadIdx.x;
  if (n >= N) return;
  float acc = 0.f;
  int beg = rowptr[n], end = rowptr[n + 1];
  for (int e = beg; e < end; ++e) {
    int s = csr[e];
    acc += xw[s] * dinv[s];
  }
  float z = acc * dinv[n] + gcn_b[0];
  out[n] = 1.f / (1.f + expf(-z));
}

extern "C" void kernel_launch(void* const* d_in, const int* in_sizes, int n_in,
                              void* d_out, int out_size, void* d_ws, size_t ws_size,
                              hipStream_t stream) {
  const float* x = (const float*)d_in[0];
  const int* ei = (const int*)d_in[1];
  const float* proj_W = (const float*)d_in[2];
  const float* proj_b = (const float*)d_in[3];
  const float* gat_W = (const float*)d_in[4];
  const float* gat_as = (const float*)d_in[5];
  const float* gat_ad = (const float*)d_in[6];
  const float* gat_bias = (const float*)d_in[7];
  const float* ln_g = (const float*)d_in[8];
  const float* ln_b = (const float*)d_in[9];
  const float* gcn_W = (const float*)d_in[10];
  const float* gcn_b = (const float*)d_in[11];
  float* out = (float*)d_out;

  const int N = in_sizes[0] / INDIM;  // 40000
  const int E = in_sizes[1] / 2;      // 320000
  const int TOT = E + N;

  size_t off = 0;
  auto alloc = [&](size_t bytes) {
    void* p = (char*)d_ws + off;
    off += (bytes + 255) & ~(size_t)255;
    return p;
  };
  float* h = (float*)alloc((size_t)MPAD * HID * 4);
  unsigned short* hb = (unsigned short*)alloc((size_t)MPAD * HID * 2);
  unsigned short* aggF = (unsigned short*)alloc((size_t)MPAD * HEADS * HID * 2);
  unsigned short* xbF = (unsigned short*)alloc((size_t)MPAD * INDIM * 2);
  unsigned short* WtPF = (unsigned short*)alloc((size_t)HID * INDIM * 2);
  unsigned short* Wt2F = (unsigned short*)alloc((size_t)NGAT * HID * HEADS * HID * 2);
  float* w_s = (float*)alloc((size_t)NGAT * HEADS * HID * 4);
  float* w_d = (float*)alloc((size_t)NGAT * HEADS * HID * 4);
  float* a_s = (float*)alloc((size_t)MPAD * HEADS * 4);
  float* a_d = (float*)alloc((size_t)MPAD * HEADS * 4);
  int* deg = (int*)alloc((size_t)N * 4);
  int* rowptr = (int*)alloc((size_t)(N + 1) * 4);
  int* cursor = (int*)alloc((size_t)N * 4);
  int* csr = (int*)alloc((size_t)TOT * 4);
  int* bsums = (int*)alloc(1024);
  float* dinv = (float*)alloc((size_t)N * 4);
  float* xw = (float*)alloc((size_t)MPAD * 4);
  (void)ws_size;

  const int NBLK = (N + 255) / 256;
  const int EBLK = (TOT + 255) / 256;
  const int WBLK = (N + 3) / 4;

  // CSR build
  hipMemsetAsync(deg, 0, (size_t)N * 4, stream);
  k_deg<<<EBLK, 256, 0, stream>>>(ei, E, N, deg);
  k_scan1<<<NBLK, 256, 0, stream>>>(deg, N, bsums);
  k_scan2<<<1, 256, 0, stream>>>(bsums, NBLK, rowptr, N);
  k_scan3<<<NBLK, 256, 0, stream>>>(deg, N, bsums, rowptr, cursor, dinv);
  k_fill<<<EBLK, 256, 0, stream>>>(ei, E, N, cursor, csr);

  // weight/input prep (fragment layouts)
  k_wtp<<<(INDIM * HID + 255) / 256, 256, 0, stream>>>(proj_W, WtPF);
  k_wt2<<<(NGAT * HID * HEADS * HID + 255) / 256, 256, 0, stream>>>(gat_W, Wt2F);
  k_wvec<<<(NGAT * HEADS * HID + 3) / 4, 256, 0, stream>>>(gat_W, gat_as, gat_ad, w_s, w_d);
  k_xfrag<<<(MPAD * 32 + 255) / 256, 256, 0, stream>>>(x, xbF, N);

  // zero aggF pad rows (N%16==0 -> pad region is a contiguous tail)
  hipMemsetAsync(aggF + (size_t)N * HEADS * HID, 0,
                 (size_t)(MPAD - N) * HEADS * HID * 2, stream);

  // projection + layer-0 attention logits
  k_mm<<<MPAD / 64, 256, 0, stream>>>(xbF, WtPF, proj_b, w_s, w_d, h, hb, a_s, a_d);

  for (int i = 0; i < NGAT; ++i) {
    k_agg2<<<WBLK, 256, 0, stream>>>(rowptr, csr, hb, a_s, a_d, aggF, N);
    if (i < NGAT - 1) {
      k_mm2<1><<<MPAD / 64, 256, 0, stream>>>(
          aggF, Wt2F + (size_t)i * HID * HEADS * HID, gat_bias + (size_t)i * HID,
          ln_g + (size_t)i * HID, ln_b + (size_t)i * HID,
          w_s + (size_t)(i + 1) * HEADS * HID, w_d + (size_t)(i + 1) * HEADS * HID,
          h, hb, a_s, a_d, nullptr);
    } else {
      k_mm2<2><<<MPAD / 64, 256, 0, stream>>>(
          aggF, Wt2F + (size_t)i * HID * HEADS * HID, gat_bias + (size_t)i * HID,
          ln_g + (size_t)i * HID, ln_b + (size_t)i * HID, gcn_W, nullptr,
          h, hb, nullptr, nullptr, xw);
    }
  }

  // GCN head
  k_gcn<<<NBLK, 256, 0, stream>>>(rowptr, csr, xw, dinv, gcn_b, out, N);
}